// Round 13
// baseline (691.138 us; speedup 1.0000x reference)
//
#include <hip/hip_runtime.h>
#include <cstddef>
#include <cstdint>

namespace {
constexpr int B_ = 8, C_ = 128, H_ = 128, W_ = 128;
constexpr int HW_ = H_ * W_;               // 16384
constexpr size_t CHW_ = (size_t)C_ * HW_;  // 2097152
constexpr int NPIX_ = B_ * HW_;            // 131072
}

typedef __attribute__((ext_vector_type(8))) short bf16x8;
typedef __attribute__((ext_vector_type(4))) float f32x4;
typedef __attribute__((ext_vector_type(16))) float f32x16;
typedef __attribute__((ext_vector_type(2))) float f32x2;
typedef __attribute__((ext_vector_type(8))) unsigned short u16x8;
typedef __attribute__((ext_vector_type(4))) unsigned short u16x4;

__device__ inline unsigned short f2bf(float f) {
  unsigned int u = __float_as_uint(f);
  unsigned int r = u + 0x7FFFu + ((u >> 16) & 1u);
  return (unsigned short)(r >> 16);
}
__device__ inline float bf2f(unsigned short u) {
  return __uint_as_float((unsigned int)u << 16);
}

// async 16B global->LDS DMA (per-lane addr = wave base + lane*16)
__device__ inline void async_copy16(void* lds_dst, const void* gsrc) {
  __builtin_amdgcn_global_load_lds(
      (const __attribute__((address_space(1))) unsigned int*)gsrc,
      (__attribute__((address_space(3))) unsigned int*)lds_dst, 16, 0, 0);
}

// ---- conv weight prep: symmetrize, bf16, layout [tap49][grp16][oc128][ic8]
__global__ __launch_bounds__(256) void prep_w_bf16_k(
    const float* __restrict__ Wa, const float* __restrict__ Wb,
    unsigned short* __restrict__ Ta, unsigned short* __restrict__ Tb) {
  int idx = blockIdx.x * 256 + threadIdx.x;  // 802816
  int j = idx & 7;
  int o = (idx >> 3) & 127;
  int g = (idx >> 10) & 15;
  int t = idx >> 14;
  int i = g * 8 + j;
  int ky = t / 7, kx = t - ky * 7;
  size_t oi = ((size_t)(o * 128 + i) * 7 + ky) * 7 + kx;
  size_t io = ((size_t)(i * 128 + o) * 7 + ky) * 7 + kx;
  Ta[idx] = f2bf(0.5f * (Wa[oi] + Wa[io]));
  Tb[idx] = f2bf(0.5f * (Wb[oi] + Wb[io]));
}

// ---- 1x1 weight prep: bf16 fragment layout [s12][f8][lane64][j8] -----------
__global__ __launch_bounds__(256) void prep_apack_k(
    const float* __restrict__ Wg, const float* __restrict__ Wm,
    unsigned short* __restrict__ Ag, unsigned short* __restrict__ Am) {
  int idx = blockIdx.x * 256 + threadIdx.x;  // 49152
  int j = idx & 7;
  int l = (idx >> 3) & 63;
  int f = (idx >> 9) & 7;
  int s = idx >> 12;
  int m = f * 16 + (l & 15);
  int k = s * 32 + (l >> 4) * 8 + j;
  Ag[idx] = f2bf(Wg[m * 384 + k]);
  Am[idx] = f2bf(Wm[m * 384 + k]);
}

// ---- row sums of the 1x1 weights (LN folding) + sigmoid(alpha) table -------
__global__ void rowsum_k(const float* __restrict__ Wg,
                         const float* __restrict__ Wm,
                         const float* __restrict__ alpha,
                         float* __restrict__ rs, float* __restrict__ sa) {
  int t = threadIdx.x;
  const float* src = (t < 128) ? Wg : Wm;
  int row = t & 127;
  float s = 0.f;
  for (int i = 0; i < 384; ++i) s += bf2f(f2bf(src[row * 384 + i]));
  rs[t] = s;
  if (t < 128) sa[t] = 1.f / (1.f + __expf(-alpha[t]));
}

// ---- LN stats over [h_exc,h_inh,ff] + CHANNELS-LAST bf16 copies + partial
// ---- sums over (h_exc,h_inh) for the later g2 LN.
// v2: 64 px / block, float2 loads (2 px per thread) for 256B segments.
__global__ __launch_bounds__(256) void stats3_cvt_k(
    const float* __restrict__ t0, const float* __restrict__ t1,
    const float* __restrict__ t2, float* __restrict__ mu_o,
    float* __restrict__ inv_o, float* __restrict__ ps12,
    float* __restrict__ pq12, unsigned short* __restrict__ o0,
    unsigned short* __restrict__ o1, unsigned short* __restrict__ o2) {
  __shared__ unsigned short tile[64 * 136];
  __shared__ float s8[8][64];
  __shared__ float q8[8][64];
  int blk = blockIdx.x;  // 2048 = 8 b x 256
  int b = blk >> 8;
  int p0 = (blk & 255) * 64;
  int t = threadIdx.x;
  int px2 = (t & 31) * 2, cq = t >> 5;
  size_t base = (size_t)b * CHW_ + p0 + px2;
  int pixg = b * HW_ + p0;
  float s0a = 0.f, s0b = 0.f, q0a = 0.f, q0b = 0.f;
  // tensor 0 (h_exc)
  for (int ci = 0; ci < 16; ++ci) {
    int c = cq * 16 + ci;
    f32x2 v = *(const f32x2*)(t0 + base + (size_t)c * HW_);
    s0a += v[0]; q0a = fmaf(v[0], v[0], q0a);
    s0b += v[1]; q0b = fmaf(v[1], v[1], q0b);
    tile[px2 * 136 + c] = f2bf(v[0]);
    tile[(px2 + 1) * 136 + c] = f2bf(v[1]);
  }
  __syncthreads();
#pragma unroll
  for (int pass = 0; pass < 4; ++pass) {
    int u = pass * 256 + t;
    int ppx = u >> 4, cg = u & 15;
    *(u16x8*)(o0 + (size_t)(pixg + ppx) * 128 + cg * 8) =
        *(const u16x8*)(tile + ppx * 136 + cg * 8);
  }
  __syncthreads();
  // tensor 1 (h_inh)
  for (int ci = 0; ci < 16; ++ci) {
    int c = cq * 16 + ci;
    f32x2 v = *(const f32x2*)(t1 + base + (size_t)c * HW_);
    s0a += v[0]; q0a = fmaf(v[0], v[0], q0a);
    s0b += v[1]; q0b = fmaf(v[1], v[1], q0b);
    tile[px2 * 136 + c] = f2bf(v[0]);
    tile[(px2 + 1) * 136 + c] = f2bf(v[1]);
  }
  s8[cq][px2] = s0a;
  s8[cq][px2 + 1] = s0b;
  q8[cq][px2] = q0a;
  q8[cq][px2 + 1] = q0b;
  __syncthreads();
#pragma unroll
  for (int pass = 0; pass < 4; ++pass) {
    int u = pass * 256 + t;
    int ppx = u >> 4, cg = u & 15;
    *(u16x8*)(o1 + (size_t)(pixg + ppx) * 128 + cg * 8) =
        *(const u16x8*)(tile + ppx * 136 + cg * 8);
  }
  if (t < 64) {
    float ss = 0.f, qs = 0.f;
#pragma unroll
    for (int k = 0; k < 8; ++k) { ss += s8[k][t]; qs += q8[k][t]; }
    ps12[pixg + t] = ss;
    pq12[pixg + t] = qs;
  }
  __syncthreads();
  // tensor 2 (ff)
  for (int ci = 0; ci < 16; ++ci) {
    int c = cq * 16 + ci;
    f32x2 v = *(const f32x2*)(t2 + base + (size_t)c * HW_);
    s0a += v[0]; q0a = fmaf(v[0], v[0], q0a);
    s0b += v[1]; q0b = fmaf(v[1], v[1], q0b);
    tile[px2 * 136 + c] = f2bf(v[0]);
    tile[(px2 + 1) * 136 + c] = f2bf(v[1]);
  }
  s8[cq][px2] = s0a;
  s8[cq][px2 + 1] = s0b;
  q8[cq][px2] = q0a;
  q8[cq][px2 + 1] = q0b;
  __syncthreads();
#pragma unroll
  for (int pass = 0; pass < 4; ++pass) {
    int u = pass * 256 + t;
    int ppx = u >> 4, cg = u & 15;
    *(u16x8*)(o2 + (size_t)(pixg + ppx) * 128 + cg * 8) =
        *(const u16x8*)(tile + ppx * 136 + cg * 8);
  }
  if (t < 64) {
    float ss = 0.f, qs = 0.f;
#pragma unroll
    for (int k = 0; k < 8; ++k) { ss += s8[k][t]; qs += q8[k][t]; }
    float m = ss * (1.f / 384.f);
    float var = qs * (1.f / 384.f) - m * m;
    mu_o[pixg + t] = m;
    inv_o[pixg + t] = rsqrtf(var + 1e-5f);
  }
}

// ---- MFMA 1x1-conv gate GEMM, ALL-channels-last B operands -----------------
template <int FINAL>
__global__ __launch_bounds__(256) void gemm_mfma_k(
    const unsigned short* __restrict__ Apack, const float* __restrict__ rowsum,
    const float* __restrict__ bias, const unsigned short* __restrict__ B0,
    const unsigned short* __restrict__ B1, const unsigned short* __restrict__ B2,
    const float* __restrict__ mu, const float* __restrict__ inv,
    const unsigned short* __restrict__ mult_cl, unsigned short* __restrict__ out_cl,
    const unsigned short* __restrict__ c2_cl, const float* __restrict__ muc,
    const float* __restrict__ invc, const unsigned short* __restrict__ inh_cl,
    const unsigned short* __restrict__ hexc_cl, const float* __restrict__ c2g,
    const float* __restrict__ c2b, const float* __restrict__ kap,
    const float* __restrict__ omg, float* __restrict__ out_f32) {
  int b = blockIdx.y;
  int tid = threadIdx.x;
  int lane = tid & 63, wid = tid >> 6;
  int l15 = lane & 15, kg = lane >> 4;
  int n0 = blockIdx.x * 128 + wid * 32;
  int pix0 = b * HW_ + n0;
  size_t bofs = (size_t)b * CHW_;
  f32x4 acc[8][2] = {};
#pragma unroll
  for (int s = 0; s < 12; ++s) {
    const unsigned short* src = (s < 4) ? B0 : ((s < 8) ? B1 : B2);
    int ch0 = (s & 3) * 32 + kg * 8;
    bf16x8 bfr[2];
#pragma unroll
    for (int nf = 0; nf < 2; ++nf)
      bfr[nf] = *(const bf16x8*)(src + (size_t)(pix0 + nf * 16 + l15) * 128 + ch0);
    const bf16x8* ap = (const bf16x8*)(Apack + ((size_t)(s * 8) * 64 + lane) * 8);
#pragma unroll
    for (int f = 0; f < 8; ++f) {
      bf16x8 afr = ap[f * 64];
#pragma unroll
      for (int nf = 0; nf < 2; ++nf)
        acc[f][nf] = __builtin_amdgcn_mfma_f32_16x16x32_bf16(afr, bfr[nf],
                                                             acc[f][nf], 0, 0, 0);
    }
  }
#pragma unroll
  for (int nf = 0; nf < 2; ++nf) {
    int n = n0 + nf * 16 + l15;
    int qpix = b * HW_ + n;
    float muv = mu[qpix], invv = inv[qpix];
    if (!FINAL) {
#pragma unroll
      for (int mf = 0; mf < 8; ++mf) {
        int m0 = mf * 16 + kg * 4;
        f32x4 rs4 = *(const f32x4*)(rowsum + m0);
        f32x4 bi4 = *(const f32x4*)(bias + m0);
        u16x4 mv = *(const u16x4*)(mult_cl + (size_t)qpix * 128 + m0);
        u16x4 st;
#pragma unroll
        for (int j = 0; j < 4; ++j) {
          float val = invv * (acc[mf][nf][j] - muv * rs4[j]) + bi4[j];
          float g = 1.f / (1.f + __expf(-val));
          st[j] = f2bf(bf2f(mv[j]) * g);
        }
        *(u16x4*)(out_cl + (size_t)qpix * 128 + m0) = st;
      }
    } else {
      float mcv = muc[qpix], icv = invc[qpix];
#pragma unroll
      for (int mf = 0; mf < 8; ++mf) {
        int m0 = mf * 16 + kg * 4;
        f32x4 rs4 = *(const f32x4*)(rowsum + m0);
        f32x4 bi4 = *(const f32x4*)(bias + m0);
        f32x4 g4 = *(const f32x4*)(c2g + m0);
        f32x4 b4 = *(const f32x4*)(c2b + m0);
        f32x4 k4 = *(const f32x4*)(kap + m0);
        f32x4 o4 = *(const f32x4*)(omg + m0);
        u16x4 c2v = *(const u16x4*)(c2_cl + (size_t)qpix * 128 + m0);
        u16x4 iv4 = *(const u16x4*)(inh_cl + (size_t)qpix * 128 + m0);
        u16x4 hx4 = *(const u16x4*)(hexc_cl + (size_t)qpix * 128 + m0);
#pragma unroll
        for (int j = 0; j < 4; ++j) {
          float val = invv * (acc[mf][nf][j] - muv * rs4[j]) + bi4[j];
          float g2 = 1.f / (1.f + __expf(-val));
          float c2 = (bf2f(c2v[j]) - mcv) * icv * g4[j] + b4[j];
          float iv = bf2f(iv4[j]);
          float ht =
              fmaxf(k4[j] * (iv + c2) + fmaxf(o4[j], 0.f) * (iv * c2), 0.f);
          out_f32[bofs + (size_t)(m0 + j) * HW_ + n] =
              (1.f - g2) * bf2f(hx4[j]) + g2 * ht;
        }
      }
    }
  }
}

// ==== conv7 staging (round-9 proven): DMA weights + register-path input =====
#define CONV_STAGE(Wp, in_cl)                                                  \
  {                                                                            \
    const unsigned short* wsrc =                                               \
        (Wp) + (size_t)(ky * 7) * 16384 + c4 * 4096 + tid * 8;                 \
    _Pragma("unroll") for (int kx = 0; kx < 7; ++kx) {                         \
      _Pragma("unroll") for (int h = 0; h < 2; ++h) {                          \
        async_copy16(w_s + kx * 4096 + (h * 256 + tid) * 8,                    \
                     wsrc + kx * 16384 + h * 2048);                            \
      }                                                                        \
    }                                                                          \
    for (int u = tid; u < 1088; u += 256) {                                    \
      int r = u / 544;                                                         \
      int rem = u - r * 544;                                                   \
      int g = rem / 136;                                                       \
      int xi = rem - g * 136;                                                  \
      int x = xi - 3;                                                          \
      int y = ybase + r;                                                       \
      u16x8 v = {};                                                            \
      if (x >= 0 && x < 128 && y >= 0 && y < 128)                              \
        v = *(const u16x8*)((in_cl) +                                          \
                            ((size_t)((b * 128 + y) * 128 + x) * 128 +         \
                             c4 * 32 + g * 8));                                \
      *(u16x8*)(in_s + u * 8) = v;                                             \
    }                                                                          \
  }

// ==== conv7 32x32x16 compute phase ==========================================
// Wave (wm,row): 64oc x 128px. A: oc=l31(+mf*32), ic=lh*8+j. B: px=l31(+nf*32).
#define CONV_COMPUTE32                                                         \
  for (int kx = 0; kx < 7; ++kx) {                                             \
    bf16x8 bfr[2][4], afr[2][2];                                               \
    _Pragma("unroll") for (int ks = 0; ks < 2; ++ks) {                         \
      int g = ks * 2 + lh;                                                     \
      _Pragma("unroll") for (int nf = 0; nf < 4; ++nf) bfr[ks][nf] =           \
          *(const bf16x8*)(in_s +                                              \
                           ((row * 4 + g) * 136 + nf * 32 + l31 + kx) * 8);    \
      _Pragma("unroll") for (int mf = 0; mf < 2; ++mf) afr[ks][mf] =           \
          *(const bf16x8*)(w_s +                                               \
                           ((kx * 4 + g) * 128 + wm * 64 + mf * 32 + l31) * 8);\
    }                                                                          \
    _Pragma("unroll") for (int ks = 0; ks < 2; ++ks)                           \
        _Pragma("unroll") for (int mf = 0; mf < 2; ++mf)                       \
            _Pragma("unroll") for (int nf = 0; nf < 4; ++nf) acc[mf][nf] =     \
                __builtin_amdgcn_mfma_f32_32x32x16_bf16(afr[ks][mf],           \
                                                        bfr[ks][nf],           \
                                                        acc[mf][nf], 0, 0, 0); \
  }

// ---- conv7 PLAIN: store conv result cl + own LN stats ----------------------
__global__ __launch_bounds__(256, 2) void conv7_plain_k(
    const unsigned short* __restrict__ in_cl,
    const unsigned short* __restrict__ Wp, unsigned short* __restrict__ out,
    float* __restrict__ mu_o, float* __restrict__ inv_o) {
  __shared__ short w_s[7 * 4 * 128 * 8];   // 57344 B
  __shared__ short in_s[2 * 4 * 136 * 8];  // 17408 B
  int b = blockIdx.x & 7;
  int y0 = ((blockIdx.x >> 3) & 63) * 2;
  int tid = threadIdx.x;
  int lane = tid & 63;
  int wid = tid >> 6;
  int wm = wid >> 1;
  int row = wid & 1;
  int l31 = lane & 31, lh = lane >> 5;
  f32x16 acc[2][4] = {};
  for (int ky = 0; ky < 7; ++ky) {
    int ybase = y0 + ky - 3;
    for (int c4 = 0; c4 < 4; ++c4) {
      __syncthreads();
      CONV_STAGE(Wp, in_cl)
      __syncthreads();
      CONV_COMPUTE32
    }
  }
  __syncthreads();
  float* red = (float*)in_s;
  int y = y0 + row;
#pragma unroll
  for (int nf = 0; nf < 4; ++nf) {
    int x = nf * 32 + l31;
    size_t paddr = (size_t)(b * HW_ + y * 128 + x) * 128;
    float s = 0.f, qq = 0.f;
#pragma unroll
    for (int mf = 0; mf < 2; ++mf) {
#pragma unroll
      for (int q = 0; q < 4; ++q) {
        int oc0 = wm * 64 + mf * 32 + lh * 4 + q * 8;
        u16x4 st;
#pragma unroll
        for (int j = 0; j < 4; ++j) {
          unsigned short bv = f2bf(acc[mf][nf][q * 4 + j]);
          float vr = bf2f(bv);
          s += vr;
          qq = fmaf(vr, vr, qq);
          st[j] = bv;
        }
        *(u16x4*)(out + paddr + oc0) = st;
      }
    }
    s += __shfl_xor(s, 32);
    qq += __shfl_xor(qq, 32);
    if (lh == 0) {
      red[(wm * 2 + row) * 128 + x] = s;
      red[512 + (wm * 2 + row) * 128 + x] = qq;
    }
  }
  __syncthreads();
  {
    int r2 = tid >> 7, x2 = tid & 127;
    float s = red[r2 * 128 + x2] + red[(2 + r2) * 128 + x2];
    float qq = red[512 + r2 * 128 + x2] + red[512 + (2 + r2) * 128 + x2];
    float m = s * (1.f / 128.f);
    float var = qq * (1.f / 128.f) - m * m;
    int q = b * HW_ + (y0 + r2) * 128 + x2;
    mu_o[q] = m;
    inv_o[q] = rsqrtf(var + 1e-5f);
  }
}

// ---- conv7 FUSED: LN(c1)+inhibit in-register, writes INHIBITED cl ----------
__global__ __launch_bounds__(256, 2) void conv7_inh_k(
    const unsigned short* __restrict__ in_cl,
    const unsigned short* __restrict__ Wp, unsigned short* out,
    float* __restrict__ mu_o, float* __restrict__ inv_o,
    const unsigned short* ff_cl, const unsigned short* __restrict__ hinh_cl,
    const float* __restrict__ ps12, const float* __restrict__ pq12,
    const float* __restrict__ sig_alpha, const float* __restrict__ mu_p,
    const float* __restrict__ gamma, const float* __restrict__ beta) {
  __shared__ short w_s[7 * 4 * 128 * 8];   // 57344 B
  __shared__ short in_s[2 * 4 * 136 * 8];  // 17408 B
  int b = blockIdx.x & 7;
  int y0 = ((blockIdx.x >> 3) & 63) * 2;
  int tid = threadIdx.x;
  int lane = tid & 63;
  int wid = tid >> 6;
  int wm = wid >> 1;
  int row = wid & 1;
  int l31 = lane & 31, lh = lane >> 5;
  f32x16 acc[2][4] = {};
  for (int ky = 0; ky < 7; ++ky) {
    int ybase = y0 + ky - 3;
    for (int c4 = 0; c4 < 4; ++c4) {
      __syncthreads();
      CONV_STAGE(Wp, in_cl)
      __syncthreads();
      CONV_COMPUTE32
    }
  }
  __syncthreads();
  float* red = (float*)in_s;  // [0..511]=s, [512..1023]=q, [1024..1535]=mu/inv
  int y = y0 + row;
  // phase A: LN stats of bf16-rounded conv result
#pragma unroll
  for (int nf = 0; nf < 4; ++nf) {
    int x = nf * 32 + l31;
    float s = 0.f, qq = 0.f;
#pragma unroll
    for (int mf = 0; mf < 2; ++mf) {
#pragma unroll
      for (int j = 0; j < 16; ++j) {
        float vr = bf2f(f2bf(acc[mf][nf][j]));
        s += vr;
        qq = fmaf(vr, vr, qq);
      }
    }
    s += __shfl_xor(s, 32);
    qq += __shfl_xor(qq, 32);
    if (lh == 0) {
      red[(wm * 2 + row) * 128 + x] = s;
      red[512 + (wm * 2 + row) * 128 + x] = qq;
    }
  }
  __syncthreads();
  // phase B: finalize c1 LN stats into LDS
  {
    int r2 = tid >> 7, x2 = tid & 127;
    float s = red[r2 * 128 + x2] + red[(2 + r2) * 128 + x2];
    float qq = red[512 + r2 * 128 + x2] + red[512 + (2 + r2) * 128 + x2];
    float m = s * (1.f / 128.f);
    float var = qq * (1.f / 128.f) - m * m;
    red[1024 + r2 * 128 + x2] = m;
    red[1280 + r2 * 128 + x2] = rsqrtf(var + 1e-5f);
  }
  __syncthreads();
  // phase C: LN + inhibit in-register, write inhibited, sum for g2 LN
  float muvA[4], invvA[4];
#pragma unroll
  for (int nf = 0; nf < 4; ++nf) {
    muvA[nf] = red[1024 + row * 128 + nf * 32 + l31];
    invvA[nf] = red[1280 + row * 128 + nf * 32 + l31];
  }
  float s2a[4] = {0.f, 0.f, 0.f, 0.f};
  float q2a[4] = {0.f, 0.f, 0.f, 0.f};
#pragma unroll
  for (int mf = 0; mf < 2; ++mf) {
#pragma unroll
    for (int q = 0; q < 4; ++q) {
      int oc0 = wm * 64 + mf * 32 + lh * 4 + q * 8;
      f32x4 ga = *(const f32x4*)(gamma + oc0);
      f32x4 be = *(const f32x4*)(beta + oc0);
      f32x4 sav = *(const f32x4*)(sig_alpha + oc0);
      f32x4 mp = *(const f32x4*)(mu_p + oc0);
#pragma unroll
      for (int nf = 0; nf < 4; ++nf) {
        int x = nf * 32 + l31;
        size_t paddr = (size_t)(b * HW_ + y * 128 + x) * 128;
        u16x4 ffv = *(const u16x4*)(ff_cl + paddr + oc0);
        u16x4 hiv = *(const u16x4*)(hinh_cl + paddr + oc0);
        u16x4 st;
#pragma unroll
        for (int j = 0; j < 4; ++j) {
          float c1 = (bf2f(f2bf(acc[mf][nf][q * 4 + j])) - muvA[nf]) *
                         invvA[nf] * ga[j] +
                     be[j];
          float r = fmaxf((sav[j] * bf2f(hiv[j]) + mp[j]) * c1, 0.f);
          float v = fmaxf(bf2f(ffv[j]) - r, 0.f);
          unsigned short bv = f2bf(v);
          float vr = bf2f(bv);
          s2a[nf] += vr;
          q2a[nf] = fmaf(vr, vr, q2a[nf]);
          st[j] = bv;
        }
        *(u16x4*)(out + paddr + oc0) = st;
      }
    }
  }
#pragma unroll
  for (int nf = 0; nf < 4; ++nf) {
    float s2 = s2a[nf] + __shfl_xor(s2a[nf], 32);
    float q2 = q2a[nf] + __shfl_xor(q2a[nf], 32);
    if (lh == 0) {
      int x = nf * 32 + l31;
      red[(wm * 2 + row) * 128 + x] = s2;
      red[512 + (wm * 2 + row) * 128 + x] = q2;
    }
  }
  __syncthreads();
  // phase D: g2 LN stats = inhibited sums + (h_exc,h_inh) partials
  {
    int r2 = tid >> 7, x2 = tid & 127;
    float s = red[r2 * 128 + x2] + red[(2 + r2) * 128 + x2];
    float qq = red[512 + r2 * 128 + x2] + red[512 + (2 + r2) * 128 + x2];
    int pg = b * HW_ + (y0 + r2) * 128 + x2;
    s += ps12[pg];
    qq += pq12[pg];
    float m = s * (1.f / 384.f);
    float var = qq * (1.f / 384.f) - m * m;
    mu_o[pg] = m;
    inv_o[pg] = rsqrtf(var + 1e-5f);
  }
}

extern "C" void kernel_launch(void* const* d_in, const int* in_sizes, int n_in,
                              void* d_out, int out_size, void* d_ws,
                              size_t ws_size, hipStream_t stream) {
  const float* ff     = (const float*)d_in[0];
  const float* h_exc  = (const float*)d_in[1];
  const float* h_inh  = (const float*)d_in[2];
  const float* W_gain = (const float*)d_in[3];
  const float* b_gain = (const float*)d_in[4];
  const float* W_mix  = (const float*)d_in[5];
  const float* b_mix  = (const float*)d_in[6];
  const float* W_inh  = (const float*)d_in[7];
  const float* W_exc  = (const float*)d_in[8];
  const float* alpha  = (const float*)d_in[9];
  const float* mu_p   = (const float*)d_in[10];
  const float* kappa  = (const float*)d_in[11];
  const float* omega  = (const float*)d_in[12];
  const float* c1_g   = (const float*)d_in[13];
  const float* c1_b   = (const float*)d_in[14];
  const float* c2_g   = (const float*)d_in[15];
  const float* c2_b   = (const float*)d_in[16];

  float* w = (float*)d_ws;
  unsigned short* Wp_inh = (unsigned short*)w;  w += 401408;
  unsigned short* Wp_exc = (unsigned short*)w;  w += 401408;
  unsigned short* Ag     = (unsigned short*)w;  w += 24576;
  unsigned short* Am     = (unsigned short*)w;  w += 24576;
  float* rs     = w;  w += 256;
  float* sa     = w;  w += 128;    // sigmoid(alpha)
  float* mu1    = w;  w += NPIX_;
  float* inv1   = w;  w += NPIX_;
  float* mu2    = w;  w += NPIX_;
  float* inv2   = w;  w += NPIX_;
  float* mu_c2  = w;  w += NPIX_;
  float* inv_c2 = w;  w += NPIX_;
  float* ps12   = w;  w += NPIX_;
  float* pq12   = w;  w += NPIX_;
  unsigned short* exc_cl   = (unsigned short*)w;  w += 8388608;
  unsigned short* hinh_cl  = (unsigned short*)w;  w += 8388608;
  unsigned short* ffinh_cl = (unsigned short*)w;  w += 8388608;  // ff -> inhibited
  unsigned short* conv_cl  = (unsigned short*)w;  w += 8388608;  // c2raw

  unsigned short* gated_cl = (unsigned short*)d_out;  // dead before final write

  prep_w_bf16_k<<<3136, 256, 0, stream>>>(W_inh, W_exc, Wp_inh, Wp_exc);
  prep_apack_k<<<192, 256, 0, stream>>>(W_gain, W_mix, Ag, Am);
  rowsum_k<<<1, 256, 0, stream>>>(W_gain, W_mix, alpha, rs, sa);

  // g1 LN stats + channels-last bf16 copies + (h_exc,h_inh) partials for g2
  stats3_cvt_k<<<2048, 256, 0, stream>>>(h_exc, h_inh, ff, mu1, inv1, ps12,
                                         pq12, exc_cl, hinh_cl, ffinh_cl);
  // gated = h_exc * g1  (bf16 channels-last into d_out)
  {
    dim3 g(128, 8);
    gemm_mfma_k<0><<<g, 256, 0, stream>>>(
        Ag, rs, b_gain, exc_cl, hinh_cl, ffinh_cl, mu1, inv1, exc_cl, gated_cl,
        nullptr, nullptr, nullptr, nullptr, nullptr, nullptr, nullptr, nullptr,
        nullptr, nullptr);
  }
  // c1 = sym_conv(gated) with FUSED LN+inhibit+g2-stats epilogue.
  conv7_inh_k<<<512, 256, 0, stream>>>(gated_cl, Wp_inh, ffinh_cl, mu2, inv2,
                                       ffinh_cl, hinh_cl, ps12, pq12, sa, mu_p,
                                       c1_g, c1_b);
  // c2 = sym_conv(inhibited) + plain LN-stats epilogue
  conv7_plain_k<<<512, 256, 0, stream>>>(ffinh_cl, Wp_exc, conv_cl, mu_c2,
                                         inv_c2);
  // g2 gemm + fused final mix -> d_out f32 NCHW
  {
    dim3 g(128, 8);
    gemm_mfma_k<1><<<g, 256, 0, stream>>>(
        Am, rs + 128, b_mix, ffinh_cl, exc_cl, hinh_cl, mu2, inv2, nullptr,
        nullptr, conv_cl, mu_c2, inv_c2, ffinh_cl, exc_cl, c2_g, c2_b, kappa,
        omega, (float*)d_out);
  }
}

// Round 14
// 591.751 us; speedup vs baseline: 1.1680x; 1.1680x over previous
//
#include <hip/hip_runtime.h>
#include <cstddef>
#include <cstdint>

namespace {
constexpr int B_ = 8, C_ = 128, H_ = 128, W_ = 128;
constexpr int HW_ = H_ * W_;               // 16384
constexpr size_t CHW_ = (size_t)C_ * HW_;  // 2097152
constexpr int NPIX_ = B_ * HW_;            // 131072
}

typedef __attribute__((ext_vector_type(8))) short bf16x8;
typedef __attribute__((ext_vector_type(4))) float f32x4;
typedef __attribute__((ext_vector_type(2))) float f32x2;
typedef __attribute__((ext_vector_type(8))) unsigned short u16x8;
typedef __attribute__((ext_vector_type(4))) unsigned short u16x4;

__device__ inline unsigned short f2bf(float f) {
  unsigned int u = __float_as_uint(f);
  unsigned int r = u + 0x7FFFu + ((u >> 16) & 1u);
  return (unsigned short)(r >> 16);
}
__device__ inline float bf2f(unsigned short u) {
  return __uint_as_float((unsigned int)u << 16);
}

// async 16B global->LDS DMA (per-lane addr = wave base + lane*16)
__device__ inline void async_copy16(void* lds_dst, const void* gsrc) {
  __builtin_amdgcn_global_load_lds(
      (const __attribute__((address_space(1))) unsigned int*)gsrc,
      (__attribute__((address_space(3))) unsigned int*)lds_dst, 16, 0, 0);
}

// ---- conv weight prep: symmetrize, bf16, layout [tap49][grp16][oc128][ic8]
__global__ __launch_bounds__(256) void prep_w_bf16_k(
    const float* __restrict__ Wa, const float* __restrict__ Wb,
    unsigned short* __restrict__ Ta, unsigned short* __restrict__ Tb) {
  int idx = blockIdx.x * 256 + threadIdx.x;  // 802816
  int j = idx & 7;
  int o = (idx >> 3) & 127;
  int g = (idx >> 10) & 15;
  int t = idx >> 14;
  int i = g * 8 + j;
  int ky = t / 7, kx = t - ky * 7;
  size_t oi = ((size_t)(o * 128 + i) * 7 + ky) * 7 + kx;
  size_t io = ((size_t)(i * 128 + o) * 7 + ky) * 7 + kx;
  Ta[idx] = f2bf(0.5f * (Wa[oi] + Wa[io]));
  Tb[idx] = f2bf(0.5f * (Wb[oi] + Wb[io]));
}

// ---- 1x1 weight prep: bf16 fragment layout [s12][f8][lane64][j8] -----------
__global__ __launch_bounds__(256) void prep_apack_k(
    const float* __restrict__ Wg, const float* __restrict__ Wm,
    unsigned short* __restrict__ Ag, unsigned short* __restrict__ Am) {
  int idx = blockIdx.x * 256 + threadIdx.x;  // 49152
  int j = idx & 7;
  int l = (idx >> 3) & 63;
  int f = (idx >> 9) & 7;
  int s = idx >> 12;
  int m = f * 16 + (l & 15);
  int k = s * 32 + (l >> 4) * 8 + j;
  Ag[idx] = f2bf(Wg[m * 384 + k]);
  Am[idx] = f2bf(Wm[m * 384 + k]);
}

// ---- row sums of the 1x1 weights (LN folding) + sigmoid(alpha) table -------
__global__ void rowsum_k(const float* __restrict__ Wg,
                         const float* __restrict__ Wm,
                         const float* __restrict__ alpha,
                         float* __restrict__ rs, float* __restrict__ sa) {
  int t = threadIdx.x;
  const float* src = (t < 128) ? Wg : Wm;
  int row = t & 127;
  float s = 0.f;
  for (int i = 0; i < 384; ++i) s += bf2f(f2bf(src[row * 384 + i]));
  rs[t] = s;
  if (t < 128) sa[t] = 1.f / (1.f + __expf(-alpha[t]));
}

// ---- LN stats over [h_exc,h_inh,ff] + CHANNELS-LAST bf16 copies + partial
// ---- sums over (h_exc,h_inh) for the later g2 LN.
// v2: 64 px / block, float2 loads (2 px per thread) for 256B segments.
__global__ __launch_bounds__(256) void stats3_cvt_k(
    const float* __restrict__ t0, const float* __restrict__ t1,
    const float* __restrict__ t2, float* __restrict__ mu_o,
    float* __restrict__ inv_o, float* __restrict__ ps12,
    float* __restrict__ pq12, unsigned short* __restrict__ o0,
    unsigned short* __restrict__ o1, unsigned short* __restrict__ o2) {
  __shared__ unsigned short tile[64 * 136];
  __shared__ float s8[8][64];
  __shared__ float q8[8][64];
  int blk = blockIdx.x;  // 2048 = 8 b x 256
  int b = blk >> 8;
  int p0 = (blk & 255) * 64;
  int t = threadIdx.x;
  int px2 = (t & 31) * 2, cq = t >> 5;
  size_t base = (size_t)b * CHW_ + p0 + px2;
  int pixg = b * HW_ + p0;
  float s0a = 0.f, s0b = 0.f, q0a = 0.f, q0b = 0.f;
  // tensor 0 (h_exc)
  for (int ci = 0; ci < 16; ++ci) {
    int c = cq * 16 + ci;
    f32x2 v = *(const f32x2*)(t0 + base + (size_t)c * HW_);
    s0a += v[0]; q0a = fmaf(v[0], v[0], q0a);
    s0b += v[1]; q0b = fmaf(v[1], v[1], q0b);
    tile[px2 * 136 + c] = f2bf(v[0]);
    tile[(px2 + 1) * 136 + c] = f2bf(v[1]);
  }
  __syncthreads();
#pragma unroll
  for (int pass = 0; pass < 4; ++pass) {
    int u = pass * 256 + t;
    int ppx = u >> 4, cg = u & 15;
    *(u16x8*)(o0 + (size_t)(pixg + ppx) * 128 + cg * 8) =
        *(const u16x8*)(tile + ppx * 136 + cg * 8);
  }
  __syncthreads();
  // tensor 1 (h_inh)
  for (int ci = 0; ci < 16; ++ci) {
    int c = cq * 16 + ci;
    f32x2 v = *(const f32x2*)(t1 + base + (size_t)c * HW_);
    s0a += v[0]; q0a = fmaf(v[0], v[0], q0a);
    s0b += v[1]; q0b = fmaf(v[1], v[1], q0b);
    tile[px2 * 136 + c] = f2bf(v[0]);
    tile[(px2 + 1) * 136 + c] = f2bf(v[1]);
  }
  s8[cq][px2] = s0a;
  s8[cq][px2 + 1] = s0b;
  q8[cq][px2] = q0a;
  q8[cq][px2 + 1] = q0b;
  __syncthreads();
#pragma unroll
  for (int pass = 0; pass < 4; ++pass) {
    int u = pass * 256 + t;
    int ppx = u >> 4, cg = u & 15;
    *(u16x8*)(o1 + (size_t)(pixg + ppx) * 128 + cg * 8) =
        *(const u16x8*)(tile + ppx * 136 + cg * 8);
  }
  if (t < 64) {
    float ss = 0.f, qs = 0.f;
#pragma unroll
    for (int k = 0; k < 8; ++k) { ss += s8[k][t]; qs += q8[k][t]; }
    ps12[pixg + t] = ss;
    pq12[pixg + t] = qs;
  }
  __syncthreads();
  // tensor 2 (ff)
  for (int ci = 0; ci < 16; ++ci) {
    int c = cq * 16 + ci;
    f32x2 v = *(const f32x2*)(t2 + base + (size_t)c * HW_);
    s0a += v[0]; q0a = fmaf(v[0], v[0], q0a);
    s0b += v[1]; q0b = fmaf(v[1], v[1], q0b);
    tile[px2 * 136 + c] = f2bf(v[0]);
    tile[(px2 + 1) * 136 + c] = f2bf(v[1]);
  }
  s8[cq][px2] = s0a;
  s8[cq][px2 + 1] = s0b;
  q8[cq][px2] = q0a;
  q8[cq][px2 + 1] = q0b;
  __syncthreads();
#pragma unroll
  for (int pass = 0; pass < 4; ++pass) {
    int u = pass * 256 + t;
    int ppx = u >> 4, cg = u & 15;
    *(u16x8*)(o2 + (size_t)(pixg + ppx) * 128 + cg * 8) =
        *(const u16x8*)(tile + ppx * 136 + cg * 8);
  }
  if (t < 64) {
    float ss = 0.f, qs = 0.f;
#pragma unroll
    for (int k = 0; k < 8; ++k) { ss += s8[k][t]; qs += q8[k][t]; }
    float m = ss * (1.f / 384.f);
    float var = qs * (1.f / 384.f) - m * m;
    mu_o[pixg + t] = m;
    inv_o[pixg + t] = rsqrtf(var + 1e-5f);
  }
}

// ---- MFMA 1x1-conv gate GEMM, ALL-channels-last B operands -----------------
template <int FINAL>
__global__ __launch_bounds__(256) void gemm_mfma_k(
    const unsigned short* __restrict__ Apack, const float* __restrict__ rowsum,
    const float* __restrict__ bias, const unsigned short* __restrict__ B0,
    const unsigned short* __restrict__ B1, const unsigned short* __restrict__ B2,
    const float* __restrict__ mu, const float* __restrict__ inv,
    const unsigned short* __restrict__ mult_cl, unsigned short* __restrict__ out_cl,
    const unsigned short* __restrict__ c2_cl, const float* __restrict__ muc,
    const float* __restrict__ invc, const unsigned short* __restrict__ inh_cl,
    const unsigned short* __restrict__ hexc_cl, const float* __restrict__ c2g,
    const float* __restrict__ c2b, const float* __restrict__ kap,
    const float* __restrict__ omg, float* __restrict__ out_f32) {
  int b = blockIdx.y;
  int tid = threadIdx.x;
  int lane = tid & 63, wid = tid >> 6;
  int l15 = lane & 15, kg = lane >> 4;
  int n0 = blockIdx.x * 128 + wid * 32;
  int pix0 = b * HW_ + n0;
  size_t bofs = (size_t)b * CHW_;
  f32x4 acc[8][2] = {};
#pragma unroll
  for (int s = 0; s < 12; ++s) {
    const unsigned short* src = (s < 4) ? B0 : ((s < 8) ? B1 : B2);
    int ch0 = (s & 3) * 32 + kg * 8;
    bf16x8 bfr[2];
#pragma unroll
    for (int nf = 0; nf < 2; ++nf)
      bfr[nf] = *(const bf16x8*)(src + (size_t)(pix0 + nf * 16 + l15) * 128 + ch0);
    const bf16x8* ap = (const bf16x8*)(Apack + ((size_t)(s * 8) * 64 + lane) * 8);
#pragma unroll
    for (int f = 0; f < 8; ++f) {
      bf16x8 afr = ap[f * 64];
#pragma unroll
      for (int nf = 0; nf < 2; ++nf)
        acc[f][nf] = __builtin_amdgcn_mfma_f32_16x16x32_bf16(afr, bfr[nf],
                                                             acc[f][nf], 0, 0, 0);
    }
  }
#pragma unroll
  for (int nf = 0; nf < 2; ++nf) {
    int n = n0 + nf * 16 + l15;
    int qpix = b * HW_ + n;
    float muv = mu[qpix], invv = inv[qpix];
    if (!FINAL) {
#pragma unroll
      for (int mf = 0; mf < 8; ++mf) {
        int m0 = mf * 16 + kg * 4;
        f32x4 rs4 = *(const f32x4*)(rowsum + m0);
        f32x4 bi4 = *(const f32x4*)(bias + m0);
        u16x4 mv = *(const u16x4*)(mult_cl + (size_t)qpix * 128 + m0);
        u16x4 st;
#pragma unroll
        for (int j = 0; j < 4; ++j) {
          float val = invv * (acc[mf][nf][j] - muv * rs4[j]) + bi4[j];
          float g = 1.f / (1.f + __expf(-val));
          st[j] = f2bf(bf2f(mv[j]) * g);
        }
        *(u16x4*)(out_cl + (size_t)qpix * 128 + m0) = st;
      }
    } else {
      float mcv = muc[qpix], icv = invc[qpix];
#pragma unroll
      for (int mf = 0; mf < 8; ++mf) {
        int m0 = mf * 16 + kg * 4;
        f32x4 rs4 = *(const f32x4*)(rowsum + m0);
        f32x4 bi4 = *(const f32x4*)(bias + m0);
        f32x4 g4 = *(const f32x4*)(c2g + m0);
        f32x4 b4 = *(const f32x4*)(c2b + m0);
        f32x4 k4 = *(const f32x4*)(kap + m0);
        f32x4 o4 = *(const f32x4*)(omg + m0);
        u16x4 c2v = *(const u16x4*)(c2_cl + (size_t)qpix * 128 + m0);
        u16x4 iv4 = *(const u16x4*)(inh_cl + (size_t)qpix * 128 + m0);
        u16x4 hx4 = *(const u16x4*)(hexc_cl + (size_t)qpix * 128 + m0);
#pragma unroll
        for (int j = 0; j < 4; ++j) {
          float val = invv * (acc[mf][nf][j] - muv * rs4[j]) + bi4[j];
          float g2 = 1.f / (1.f + __expf(-val));
          float c2 = (bf2f(c2v[j]) - mcv) * icv * g4[j] + b4[j];
          float iv = bf2f(iv4[j]);
          float ht =
              fmaxf(k4[j] * (iv + c2) + fmaxf(o4[j], 0.f) * (iv * c2), 0.f);
          out_f32[bofs + (size_t)(m0 + j) * HW_ + n] =
              (1.f - g2) * bf2f(hx4[j]) + g2 * ht;
        }
      }
    }
  }
}

// ---- conv7 PLAIN: round-9 staging (DMA weights + register-path input);
// ---- store conv result cl + own LN stats (full restrict) -------------------
__global__ __launch_bounds__(256, 2) void conv7_plain_k(
    const unsigned short* __restrict__ in_cl,
    const unsigned short* __restrict__ Wp, unsigned short* __restrict__ out,
    float* __restrict__ mu_o, float* __restrict__ inv_o) {
  __shared__ short w_s[7 * 4 * 128 * 8];   // 57344 B
  __shared__ short in_s[2 * 4 * 136 * 8];  // 17408 B
  int b = blockIdx.x & 7;
  int y0 = ((blockIdx.x >> 3) & 63) * 2;
  int tid = threadIdx.x;
  int lane = tid & 63;
  int wid = tid >> 6;
  int wm = wid >> 1;
  int row = wid & 1;
  int l15 = lane & 15, kg = lane >> 4;
  f32x4 acc[4][8] = {};
  for (int ky = 0; ky < 7; ++ky) {
    int ybase = y0 + ky - 3;
    for (int c4 = 0; c4 < 4; ++c4) {
      __syncthreads();
      const unsigned short* wsrc =
          Wp + (size_t)(ky * 7) * 16384 + c4 * 4096 + tid * 8;
#pragma unroll
      for (int kx = 0; kx < 7; ++kx) {
#pragma unroll
        for (int h = 0; h < 2; ++h) {
          async_copy16(w_s + kx * 4096 + (h * 256 + tid) * 8,
                       wsrc + kx * 16384 + h * 2048);
        }
      }
      for (int u = tid; u < 1088; u += 256) {
        int r = u / 544;
        int rem = u - r * 544;
        int g = rem / 136;
        int xi = rem - g * 136;
        int x = xi - 3;
        int y = ybase + r;
        u16x8 v = {};
        if (x >= 0 && x < 128 && y >= 0 && y < 128)
          v = *(const u16x8*)(in_cl + ((size_t)((b * 128 + y) * 128 + x) * 128 +
                                       c4 * 32 + g * 8));
        *(u16x8*)(in_s + u * 8) = v;
      }
      __syncthreads();
      for (int kx = 0; kx < 7; ++kx) {
        bf16x8 bfr[8], afr[4];
#pragma unroll
        for (int nf = 0; nf < 8; ++nf) {
          int xi = nf * 16 + l15 + kx;
          bfr[nf] = *(const bf16x8*)(in_s + ((row * 4 + kg) * 136 + xi) * 8);
        }
#pragma unroll
        for (int mf = 0; mf < 4; ++mf) {
          int oc = wm * 64 + mf * 16 + l15;
          afr[mf] = *(const bf16x8*)(w_s + ((kx * 4 + kg) * 128 + oc) * 8);
        }
#pragma unroll
        for (int mf = 0; mf < 4; ++mf)
#pragma unroll
          for (int nf = 0; nf < 8; ++nf)
            acc[mf][nf] = __builtin_amdgcn_mfma_f32_16x16x32_bf16(
                afr[mf], bfr[nf], acc[mf][nf], 0, 0, 0);
      }
    }
  }
  __syncthreads();
  float* red = (float*)in_s;
  int y = y0 + row;
#pragma unroll
  for (int nf = 0; nf < 8; ++nf) {
    int x = nf * 16 + l15;
    size_t paddr = (size_t)(b * HW_ + y * 128 + x) * 128;
    float s = 0.f, qq = 0.f;
#pragma unroll
    for (int mf = 0; mf < 4; ++mf) {
      int oc0 = wm * 64 + mf * 16 + kg * 4;
      u16x4 st;
#pragma unroll
      for (int j = 0; j < 4; ++j) {
        unsigned short bv = f2bf(acc[mf][nf][j]);
        float vr = bf2f(bv);
        s += vr;
        qq = fmaf(vr, vr, qq);
        st[j] = bv;
      }
      *(u16x4*)(out + paddr + oc0) = st;
    }
    s += __shfl_xor(s, 16);
    qq += __shfl_xor(qq, 16);
    s += __shfl_xor(s, 32);
    qq += __shfl_xor(qq, 32);
    if (kg == 0) {
      red[(wm * 2 + row) * 128 + x] = s;
      red[512 + (wm * 2 + row) * 128 + x] = qq;
    }
  }
  __syncthreads();
  {
    int r2 = tid >> 7, x2 = tid & 127;
    float s = red[r2 * 128 + x2] + red[(2 + r2) * 128 + x2];
    float qq = red[512 + r2 * 128 + x2] + red[512 + (2 + r2) * 128 + x2];
    float m = s * (1.f / 128.f);
    float var = qq * (1.f / 128.f) - m * m;
    int q = b * HW_ + (y0 + r2) * 128 + x2;
    mu_o[q] = m;
    inv_o[q] = rsqrtf(var + 1e-5f);
  }
}

// ---- conv7 FUSED: round-9 staging; LN(c1)+inhibit in-register, writes ------
// ---- INHIBITED cl (out aliases ff_cl); emits g2 LN stats via ps12/pq12 -----
__global__ __launch_bounds__(256, 2) void conv7_inh_k(
    const unsigned short* __restrict__ in_cl,
    const unsigned short* __restrict__ Wp, unsigned short* out,
    float* __restrict__ mu_o, float* __restrict__ inv_o,
    const unsigned short* ff_cl, const unsigned short* __restrict__ hinh_cl,
    const float* __restrict__ ps12, const float* __restrict__ pq12,
    const float* __restrict__ sig_alpha, const float* __restrict__ mu_p,
    const float* __restrict__ gamma, const float* __restrict__ beta) {
  __shared__ short w_s[7 * 4 * 128 * 8];   // 57344 B
  __shared__ short in_s[2 * 4 * 136 * 8];  // 17408 B
  int b = blockIdx.x & 7;
  int y0 = ((blockIdx.x >> 3) & 63) * 2;
  int tid = threadIdx.x;
  int lane = tid & 63;
  int wid = tid >> 6;
  int wm = wid >> 1;
  int row = wid & 1;
  int l15 = lane & 15, kg = lane >> 4;
  f32x4 acc[4][8] = {};
  for (int ky = 0; ky < 7; ++ky) {
    int ybase = y0 + ky - 3;
    for (int c4 = 0; c4 < 4; ++c4) {
      __syncthreads();
      const unsigned short* wsrc =
          Wp + (size_t)(ky * 7) * 16384 + c4 * 4096 + tid * 8;
#pragma unroll
      for (int kx = 0; kx < 7; ++kx) {
#pragma unroll
        for (int h = 0; h < 2; ++h) {
          async_copy16(w_s + kx * 4096 + (h * 256 + tid) * 8,
                       wsrc + kx * 16384 + h * 2048);
        }
      }
      for (int u = tid; u < 1088; u += 256) {
        int r = u / 544;
        int rem = u - r * 544;
        int g = rem / 136;
        int xi = rem - g * 136;
        int x = xi - 3;
        int y = ybase + r;
        u16x8 v = {};
        if (x >= 0 && x < 128 && y >= 0 && y < 128)
          v = *(const u16x8*)(in_cl + ((size_t)((b * 128 + y) * 128 + x) * 128 +
                                       c4 * 32 + g * 8));
        *(u16x8*)(in_s + u * 8) = v;
      }
      __syncthreads();
      for (int kx = 0; kx < 7; ++kx) {
        bf16x8 bfr[8], afr[4];
#pragma unroll
        for (int nf = 0; nf < 8; ++nf) {
          int xi = nf * 16 + l15 + kx;
          bfr[nf] = *(const bf16x8*)(in_s + ((row * 4 + kg) * 136 + xi) * 8);
        }
#pragma unroll
        for (int mf = 0; mf < 4; ++mf) {
          int oc = wm * 64 + mf * 16 + l15;
          afr[mf] = *(const bf16x8*)(w_s + ((kx * 4 + kg) * 128 + oc) * 8);
        }
#pragma unroll
        for (int mf = 0; mf < 4; ++mf)
#pragma unroll
          for (int nf = 0; nf < 8; ++nf)
            acc[mf][nf] = __builtin_amdgcn_mfma_f32_16x16x32_bf16(
                afr[mf], bfr[nf], acc[mf][nf], 0, 0, 0);
      }
    }
  }
  __syncthreads();
  float* red = (float*)in_s;  // [0..511]=s, [512..1023]=q, [1024..1535]=mu/inv
  int y = y0 + row;
  // phase A: LN stats of bf16-rounded conv result
#pragma unroll
  for (int nf = 0; nf < 8; ++nf) {
    int x = nf * 16 + l15;
    float s = 0.f, qq = 0.f;
#pragma unroll
    for (int mf = 0; mf < 4; ++mf) {
#pragma unroll
      for (int j = 0; j < 4; ++j) {
        float vr = bf2f(f2bf(acc[mf][nf][j]));
        s += vr;
        qq = fmaf(vr, vr, qq);
      }
    }
    s += __shfl_xor(s, 16);
    qq += __shfl_xor(qq, 16);
    s += __shfl_xor(s, 32);
    qq += __shfl_xor(qq, 32);
    if (kg == 0) {
      red[(wm * 2 + row) * 128 + x] = s;
      red[512 + (wm * 2 + row) * 128 + x] = qq;
    }
  }
  __syncthreads();
  // phase B: finalize c1 LN stats into LDS
  {
    int r2 = tid >> 7, x2 = tid & 127;
    float s = red[r2 * 128 + x2] + red[(2 + r2) * 128 + x2];
    float qq = red[512 + r2 * 128 + x2] + red[512 + (2 + r2) * 128 + x2];
    float m = s * (1.f / 128.f);
    float var = qq * (1.f / 128.f) - m * m;
    red[1024 + r2 * 128 + x2] = m;
    red[1280 + r2 * 128 + x2] = rsqrtf(var + 1e-5f);
  }
  __syncthreads();
  // phase C: LN + inhibit in-register, write inhibited, sum for g2 LN
  f32x4 ga4[4], be4[4], sa4[4], mp4[4];
#pragma unroll
  for (int mf = 0; mf < 4; ++mf) {
    int oc0 = wm * 64 + mf * 16 + kg * 4;
    ga4[mf] = *(const f32x4*)(gamma + oc0);
    be4[mf] = *(const f32x4*)(beta + oc0);
    sa4[mf] = *(const f32x4*)(sig_alpha + oc0);
    mp4[mf] = *(const f32x4*)(mu_p + oc0);
  }
#pragma unroll
  for (int nf = 0; nf < 8; ++nf) {
    int x = nf * 16 + l15;
    float muv = red[1024 + row * 128 + x];
    float invv = red[1280 + row * 128 + x];
    size_t paddr = (size_t)(b * HW_ + y * 128 + x) * 128;
    float s2 = 0.f, q2 = 0.f;
#pragma unroll
    for (int mf = 0; mf < 4; ++mf) {
      int oc0 = wm * 64 + mf * 16 + kg * 4;
      u16x4 ffv = *(const u16x4*)(ff_cl + paddr + oc0);
      u16x4 hiv = *(const u16x4*)(hinh_cl + paddr + oc0);
      u16x4 st;
#pragma unroll
      for (int j = 0; j < 4; ++j) {
        float c1 =
            (bf2f(f2bf(acc[mf][nf][j])) - muv) * invv * ga4[mf][j] + be4[mf][j];
        float r = fmaxf((sa4[mf][j] * bf2f(hiv[j]) + mp4[mf][j]) * c1, 0.f);
        float v = fmaxf(bf2f(ffv[j]) - r, 0.f);
        unsigned short bv = f2bf(v);
        float vr = bf2f(bv);
        s2 += vr;
        q2 = fmaf(vr, vr, q2);
        st[j] = bv;
      }
      *(u16x4*)(out + paddr + oc0) = st;
    }
    s2 += __shfl_xor(s2, 16);
    q2 += __shfl_xor(q2, 16);
    s2 += __shfl_xor(s2, 32);
    q2 += __shfl_xor(q2, 32);
    if (kg == 0) {
      red[(wm * 2 + row) * 128 + x] = s2;
      red[512 + (wm * 2 + row) * 128 + x] = q2;
    }
  }
  __syncthreads();
  // phase D: g2 LN stats = inhibited sums + (h_exc,h_inh) partials
  {
    int r2 = tid >> 7, x2 = tid & 127;
    float s = red[r2 * 128 + x2] + red[(2 + r2) * 128 + x2];
    float qq = red[512 + r2 * 128 + x2] + red[512 + (2 + r2) * 128 + x2];
    int pg = b * HW_ + (y0 + r2) * 128 + x2;
    s += ps12[pg];
    qq += pq12[pg];
    float m = s * (1.f / 384.f);
    float var = qq * (1.f / 384.f) - m * m;
    mu_o[pg] = m;
    inv_o[pg] = rsqrtf(var + 1e-5f);
  }
}

extern "C" void kernel_launch(void* const* d_in, const int* in_sizes, int n_in,
                              void* d_out, int out_size, void* d_ws,
                              size_t ws_size, hipStream_t stream) {
  const float* ff     = (const float*)d_in[0];
  const float* h_exc  = (const float*)d_in[1];
  const float* h_inh  = (const float*)d_in[2];
  const float* W_gain = (const float*)d_in[3];
  const float* b_gain = (const float*)d_in[4];
  const float* W_mix  = (const float*)d_in[5];
  const float* b_mix  = (const float*)d_in[6];
  const float* W_inh  = (const float*)d_in[7];
  const float* W_exc  = (const float*)d_in[8];
  const float* alpha  = (const float*)d_in[9];
  const float* mu_p   = (const float*)d_in[10];
  const float* kappa  = (const float*)d_in[11];
  const float* omega  = (const float*)d_in[12];
  const float* c1_g   = (const float*)d_in[13];
  const float* c1_b   = (const float*)d_in[14];
  const float* c2_g   = (const float*)d_in[15];
  const float* c2_b   = (const float*)d_in[16];

  float* w = (float*)d_ws;
  unsigned short* Wp_inh = (unsigned short*)w;  w += 401408;
  unsigned short* Wp_exc = (unsigned short*)w;  w += 401408;
  unsigned short* Ag     = (unsigned short*)w;  w += 24576;
  unsigned short* Am     = (unsigned short*)w;  w += 24576;
  float* rs     = w;  w += 256;
  float* sa     = w;  w += 128;    // sigmoid(alpha)
  float* mu1    = w;  w += NPIX_;
  float* inv1   = w;  w += NPIX_;
  float* mu2    = w;  w += NPIX_;
  float* inv2   = w;  w += NPIX_;
  float* mu_c2  = w;  w += NPIX_;
  float* inv_c2 = w;  w += NPIX_;
  float* ps12   = w;  w += NPIX_;
  float* pq12   = w;  w += NPIX_;
  unsigned short* exc_cl   = (unsigned short*)w;  w += 8388608;
  unsigned short* hinh_cl  = (unsigned short*)w;  w += 8388608;
  unsigned short* ffinh_cl = (unsigned short*)w;  w += 8388608;  // ff -> inhibited
  unsigned short* conv_cl  = (unsigned short*)w;  w += 8388608;  // c2raw

  unsigned short* gated_cl = (unsigned short*)d_out;  // dead before final write

  prep_w_bf16_k<<<3136, 256, 0, stream>>>(W_inh, W_exc, Wp_inh, Wp_exc);
  prep_apack_k<<<192, 256, 0, stream>>>(W_gain, W_mix, Ag, Am);
  rowsum_k<<<1, 256, 0, stream>>>(W_gain, W_mix, alpha, rs, sa);

  // g1 LN stats + channels-last bf16 copies + (h_exc,h_inh) partials for g2
  stats3_cvt_k<<<2048, 256, 0, stream>>>(h_exc, h_inh, ff, mu1, inv1, ps12,
                                         pq12, exc_cl, hinh_cl, ffinh_cl);
  // gated = h_exc * g1  (bf16 channels-last into d_out)
  {
    dim3 g(128, 8);
    gemm_mfma_k<0><<<g, 256, 0, stream>>>(
        Ag, rs, b_gain, exc_cl, hinh_cl, ffinh_cl, mu1, inv1, exc_cl, gated_cl,
        nullptr, nullptr, nullptr, nullptr, nullptr, nullptr, nullptr, nullptr,
        nullptr, nullptr);
  }
  // c1 = sym_conv(gated) with FUSED LN+inhibit+g2-stats epilogue.
  conv7_inh_k<<<512, 256, 0, stream>>>(gated_cl, Wp_inh, ffinh_cl, mu2, inv2,
                                       ffinh_cl, hinh_cl, ps12, pq12, sa, mu_p,
                                       c1_g, c1_b);
  // c2 = sym_conv(inhibited) + plain LN-stats epilogue
  conv7_plain_k<<<512, 256, 0, stream>>>(ffinh_cl, Wp_exc, conv_cl, mu_c2,
                                         inv_c2);
  // g2 gemm + fused final mix -> d_out f32 NCHW
  {
    dim3 g(128, 8);
    gemm_mfma_k<1><<<g, 256, 0, stream>>>(
        Am, rs + 128, b_mix, ffinh_cl, exc_cl, hinh_cl, mu2, inv2, nullptr,
        nullptr, conv_cl, mu_c2, inv_c2, ffinh_cl, exc_cl, c2_g, c2_b, kappa,
        omega, (float*)d_out);
  }
}

// Round 15
// 561.949 us; speedup vs baseline: 1.2299x; 1.0530x over previous
//
#include <hip/hip_runtime.h>
#include <cstddef>
#include <cstdint>

namespace {
constexpr int B_ = 8, C_ = 128, H_ = 128, W_ = 128;
constexpr int HW_ = H_ * W_;               // 16384
constexpr size_t CHW_ = (size_t)C_ * HW_;  // 2097152
constexpr int NPIX_ = B_ * HW_;            // 131072
}

typedef __attribute__((ext_vector_type(8))) short bf16x8;
typedef __attribute__((ext_vector_type(4))) float f32x4;
typedef __attribute__((ext_vector_type(2))) float f32x2;
typedef __attribute__((ext_vector_type(8))) unsigned short u16x8;
typedef __attribute__((ext_vector_type(4))) unsigned short u16x4;

__device__ inline unsigned short f2bf(float f) {
  unsigned int u = __float_as_uint(f);
  unsigned int r = u + 0x7FFFu + ((u >> 16) & 1u);
  return (unsigned short)(r >> 16);
}
__device__ inline float bf2f(unsigned short u) {
  return __uint_as_float((unsigned int)u << 16);
}

// async 16B global->LDS DMA (per-lane addr = wave base + lane*16)
__device__ inline void async_copy16(void* lds_dst, const void* gsrc) {
  __builtin_amdgcn_global_load_lds(
      (const __attribute__((address_space(1))) unsigned int*)gsrc,
      (__attribute__((address_space(3))) unsigned int*)lds_dst, 16, 0, 0);
}

// ---- conv weight prep: symmetrize, bf16, layout [tap49][grp16][oc128][ic8]
__global__ __launch_bounds__(256) void prep_w_bf16_k(
    const float* __restrict__ Wa, const float* __restrict__ Wb,
    unsigned short* __restrict__ Ta, unsigned short* __restrict__ Tb) {
  int idx = blockIdx.x * 256 + threadIdx.x;  // 802816
  int j = idx & 7;
  int o = (idx >> 3) & 127;
  int g = (idx >> 10) & 15;
  int t = idx >> 14;
  int i = g * 8 + j;
  int ky = t / 7, kx = t - ky * 7;
  size_t oi = ((size_t)(o * 128 + i) * 7 + ky) * 7 + kx;
  size_t io = ((size_t)(i * 128 + o) * 7 + ky) * 7 + kx;
  Ta[idx] = f2bf(0.5f * (Wa[oi] + Wa[io]));
  Tb[idx] = f2bf(0.5f * (Wb[oi] + Wb[io]));
}

// ---- 1x1 weight prep: bf16 fragment layout [s12][f8][lane64][j8] -----------
__global__ __launch_bounds__(256) void prep_apack_k(
    const float* __restrict__ Wg, const float* __restrict__ Wm,
    unsigned short* __restrict__ Ag, unsigned short* __restrict__ Am) {
  int idx = blockIdx.x * 256 + threadIdx.x;  // 49152
  int j = idx & 7;
  int l = (idx >> 3) & 63;
  int f = (idx >> 9) & 7;
  int s = idx >> 12;
  int m = f * 16 + (l & 15);
  int k = s * 32 + (l >> 4) * 8 + j;
  Ag[idx] = f2bf(Wg[m * 384 + k]);
  Am[idx] = f2bf(Wm[m * 384 + k]);
}

// ---- row sums of the 1x1 weights (LN folding) + sigmoid(alpha) table -------
__global__ void rowsum_k(const float* __restrict__ Wg,
                         const float* __restrict__ Wm,
                         const float* __restrict__ alpha,
                         float* __restrict__ rs, float* __restrict__ sa) {
  int t = threadIdx.x;
  const float* src = (t < 128) ? Wg : Wm;
  int row = t & 127;
  float s = 0.f;
  for (int i = 0; i < 384; ++i) s += bf2f(f2bf(src[row * 384 + i]));
  rs[t] = s;
  if (t < 128) sa[t] = 1.f / (1.f + __expf(-alpha[t]));
}

// ---- FUSED: LN stats over [h_exc,h_inh,ff] + cl bf16 copies + ps12/pq12
// ---- partials + the FULL g1 gate GEMM (per-tensor K-slices from the live
// ---- LDS tile) + gated = h_exc*g1 epilogue. Replaces stats3 + gemm0.
// Block: 64 px, 256 thr = 4 waves; wave = 16 px x 128 oc (8 mf fragments).
__global__ __launch_bounds__(256) void stats3_gate_k(
    const float* __restrict__ t0, const float* __restrict__ t1,
    const float* __restrict__ t2, const unsigned short* __restrict__ Apack,
    const float* __restrict__ rowsum, const float* __restrict__ bias,
    float* __restrict__ ps12, float* __restrict__ pq12,
    unsigned short* __restrict__ o0, unsigned short* __restrict__ o1,
    unsigned short* __restrict__ o2, unsigned short* __restrict__ gated_cl) {
  __shared__ unsigned short tile[64 * 136];  // current tensor, 64px x 128c
  __shared__ unsigned short exc2[64 * 128];  // h_exc copy for gating mult
  __shared__ float s8[8][64];
  __shared__ float q8[8][64];
  __shared__ float bc_mu[64];
  __shared__ float bc_inv[64];
  int blk = blockIdx.x;  // 2048 = 8 b x 256
  int b = blk >> 8;
  int p0 = (blk & 255) * 64;
  int t = threadIdx.x;
  int px2 = (t & 31) * 2, cq = t >> 5;
  int lane = t & 63, wv = t >> 6;
  int l15 = lane & 15, kg = lane >> 4;
  size_t base = (size_t)b * CHW_ + p0 + px2;
  int pixg = b * HW_ + p0;
  f32x4 acc[8] = {};
  float s0a = 0.f, s0b = 0.f, q0a = 0.f, q0b = 0.f;

  // ======== pass 0: h_exc ========
  for (int ci = 0; ci < 16; ++ci) {
    int c = cq * 16 + ci;
    f32x2 v = *(const f32x2*)(t0 + base + (size_t)c * HW_);
    s0a += v[0]; q0a = fmaf(v[0], v[0], q0a);
    s0b += v[1]; q0b = fmaf(v[1], v[1], q0b);
    unsigned short b0 = f2bf(v[0]), b1 = f2bf(v[1]);
    tile[px2 * 136 + c] = b0;
    tile[(px2 + 1) * 136 + c] = b1;
    exc2[px2 * 128 + c] = b0;
    exc2[(px2 + 1) * 128 + c] = b1;
  }
  __syncthreads();
#pragma unroll
  for (int pass = 0; pass < 4; ++pass) {
    int u = pass * 256 + t;
    int ppx = u >> 4, cg = u & 15;
    *(u16x8*)(o0 + (size_t)(pixg + ppx) * 128 + cg * 8) =
        *(const u16x8*)(tile + ppx * 136 + cg * 8);
  }
  // gate MFMA: K-slices 0..3 (tensor 0) from live tile
#pragma unroll
  for (int sl = 0; sl < 4; ++sl) {
    bf16x8 bfr =
        *(const bf16x8*)(tile + (wv * 16 + l15) * 136 + sl * 32 + kg * 8);
    const bf16x8* ap =
        (const bf16x8*)(Apack + ((size_t)(sl * 8) * 64 + lane) * 8);
#pragma unroll
    for (int f = 0; f < 8; ++f)
      acc[f] = __builtin_amdgcn_mfma_f32_16x16x32_bf16(ap[f * 64], bfr, acc[f],
                                                       0, 0, 0);
  }
  __syncthreads();

  // ======== pass 1: h_inh ========
  for (int ci = 0; ci < 16; ++ci) {
    int c = cq * 16 + ci;
    f32x2 v = *(const f32x2*)(t1 + base + (size_t)c * HW_);
    s0a += v[0]; q0a = fmaf(v[0], v[0], q0a);
    s0b += v[1]; q0b = fmaf(v[1], v[1], q0b);
    tile[px2 * 136 + c] = f2bf(v[0]);
    tile[(px2 + 1) * 136 + c] = f2bf(v[1]);
  }
  s8[cq][px2] = s0a;
  s8[cq][px2 + 1] = s0b;
  q8[cq][px2] = q0a;
  q8[cq][px2 + 1] = q0b;
  __syncthreads();
#pragma unroll
  for (int pass = 0; pass < 4; ++pass) {
    int u = pass * 256 + t;
    int ppx = u >> 4, cg = u & 15;
    *(u16x8*)(o1 + (size_t)(pixg + ppx) * 128 + cg * 8) =
        *(const u16x8*)(tile + ppx * 136 + cg * 8);
  }
#pragma unroll
  for (int sl = 0; sl < 4; ++sl) {
    bf16x8 bfr =
        *(const bf16x8*)(tile + (wv * 16 + l15) * 136 + sl * 32 + kg * 8);
    const bf16x8* ap =
        (const bf16x8*)(Apack + ((size_t)((4 + sl) * 8) * 64 + lane) * 8);
#pragma unroll
    for (int f = 0; f < 8; ++f)
      acc[f] = __builtin_amdgcn_mfma_f32_16x16x32_bf16(ap[f * 64], bfr, acc[f],
                                                       0, 0, 0);
  }
  if (t < 64) {
    float ss = 0.f, qs = 0.f;
#pragma unroll
    for (int k = 0; k < 8; ++k) { ss += s8[k][t]; qs += q8[k][t]; }
    ps12[pixg + t] = ss;
    pq12[pixg + t] = qs;
  }
  __syncthreads();

  // ======== pass 2: ff ========
  for (int ci = 0; ci < 16; ++ci) {
    int c = cq * 16 + ci;
    f32x2 v = *(const f32x2*)(t2 + base + (size_t)c * HW_);
    s0a += v[0]; q0a = fmaf(v[0], v[0], q0a);
    s0b += v[1]; q0b = fmaf(v[1], v[1], q0b);
    tile[px2 * 136 + c] = f2bf(v[0]);
    tile[(px2 + 1) * 136 + c] = f2bf(v[1]);
  }
  s8[cq][px2] = s0a;
  s8[cq][px2 + 1] = s0b;
  q8[cq][px2] = q0a;
  q8[cq][px2 + 1] = q0b;
  __syncthreads();
#pragma unroll
  for (int pass = 0; pass < 4; ++pass) {
    int u = pass * 256 + t;
    int ppx = u >> 4, cg = u & 15;
    *(u16x8*)(o2 + (size_t)(pixg + ppx) * 128 + cg * 8) =
        *(const u16x8*)(tile + ppx * 136 + cg * 8);
  }
#pragma unroll
  for (int sl = 0; sl < 4; ++sl) {
    bf16x8 bfr =
        *(const bf16x8*)(tile + (wv * 16 + l15) * 136 + sl * 32 + kg * 8);
    const bf16x8* ap =
        (const bf16x8*)(Apack + ((size_t)((8 + sl) * 8) * 64 + lane) * 8);
#pragma unroll
    for (int f = 0; f < 8; ++f)
      acc[f] = __builtin_amdgcn_mfma_f32_16x16x32_bf16(ap[f * 64], bfr, acc[f],
                                                       0, 0, 0);
  }
  if (t < 64) {
    float ss = 0.f, qs = 0.f;
#pragma unroll
    for (int k = 0; k < 8; ++k) { ss += s8[k][t]; qs += q8[k][t]; }
    float m = ss * (1.f / 384.f);
    float var = qs * (1.f / 384.f) - m * m;
    bc_mu[t] = m;
    bc_inv[t] = rsqrtf(var + 1e-5f);
  }
  __syncthreads();

  // ======== epilogue: g1 = sigmoid(LNfold); gated = h_exc * g1 ========
  {
    int pxl = wv * 16 + l15;
    int pix = pixg + pxl;
    float muv = bc_mu[pxl], invv = bc_inv[pxl];
#pragma unroll
    for (int f = 0; f < 8; ++f) {
      int m0 = f * 16 + kg * 4;
      f32x4 rs4 = *(const f32x4*)(rowsum + m0);
      f32x4 bi4 = *(const f32x4*)(bias + m0);
      u16x4 mv = *(const u16x4*)(exc2 + pxl * 128 + m0);
      u16x4 st;
#pragma unroll
      for (int j = 0; j < 4; ++j) {
        float val = invv * (acc[f][j] - muv * rs4[j]) + bi4[j];
        float g = 1.f / (1.f + __expf(-val));
        st[j] = f2bf(bf2f(mv[j]) * g);
      }
      *(u16x4*)(gated_cl + (size_t)pix * 128 + m0) = st;
    }
  }
}

// ---- MFMA g2 gate GEMM + fused final mix (FINAL epilogue only) -------------
__global__ __launch_bounds__(256) void gemm_final_k(
    const unsigned short* __restrict__ Apack, const float* __restrict__ rowsum,
    const float* __restrict__ bias, const unsigned short* __restrict__ B0,
    const unsigned short* __restrict__ B1, const unsigned short* __restrict__ B2,
    const float* __restrict__ mu, const float* __restrict__ inv,
    const unsigned short* __restrict__ c2_cl, const float* __restrict__ muc,
    const float* __restrict__ invc, const unsigned short* __restrict__ inh_cl,
    const unsigned short* __restrict__ hexc_cl, const float* __restrict__ c2g,
    const float* __restrict__ c2b, const float* __restrict__ kap,
    const float* __restrict__ omg, float* __restrict__ out_f32) {
  int b = blockIdx.y;
  int tid = threadIdx.x;
  int lane = tid & 63, wid = tid >> 6;
  int l15 = lane & 15, kg = lane >> 4;
  int n0 = blockIdx.x * 128 + wid * 32;
  int pix0 = b * HW_ + n0;
  size_t bofs = (size_t)b * CHW_;
  f32x4 acc[8][2] = {};
#pragma unroll
  for (int s = 0; s < 12; ++s) {
    const unsigned short* src = (s < 4) ? B0 : ((s < 8) ? B1 : B2);
    int ch0 = (s & 3) * 32 + kg * 8;
    bf16x8 bfr[2];
#pragma unroll
    for (int nf = 0; nf < 2; ++nf)
      bfr[nf] = *(const bf16x8*)(src + (size_t)(pix0 + nf * 16 + l15) * 128 + ch0);
    const bf16x8* ap = (const bf16x8*)(Apack + ((size_t)(s * 8) * 64 + lane) * 8);
#pragma unroll
    for (int f = 0; f < 8; ++f) {
      bf16x8 afr = ap[f * 64];
#pragma unroll
      for (int nf = 0; nf < 2; ++nf)
        acc[f][nf] = __builtin_amdgcn_mfma_f32_16x16x32_bf16(afr, bfr[nf],
                                                             acc[f][nf], 0, 0, 0);
    }
  }
#pragma unroll
  for (int nf = 0; nf < 2; ++nf) {
    int n = n0 + nf * 16 + l15;
    int qpix = b * HW_ + n;
    float muv = mu[qpix], invv = inv[qpix];
    float mcv = muc[qpix], icv = invc[qpix];
#pragma unroll
    for (int mf = 0; mf < 8; ++mf) {
      int m0 = mf * 16 + kg * 4;
      f32x4 rs4 = *(const f32x4*)(rowsum + m0);
      f32x4 bi4 = *(const f32x4*)(bias + m0);
      f32x4 g4 = *(const f32x4*)(c2g + m0);
      f32x4 b4 = *(const f32x4*)(c2b + m0);
      f32x4 k4 = *(const f32x4*)(kap + m0);
      f32x4 o4 = *(const f32x4*)(omg + m0);
      u16x4 c2v = *(const u16x4*)(c2_cl + (size_t)qpix * 128 + m0);
      u16x4 iv4 = *(const u16x4*)(inh_cl + (size_t)qpix * 128 + m0);
      u16x4 hx4 = *(const u16x4*)(hexc_cl + (size_t)qpix * 128 + m0);
#pragma unroll
      for (int j = 0; j < 4; ++j) {
        float val = invv * (acc[mf][nf][j] - muv * rs4[j]) + bi4[j];
        float g2 = 1.f / (1.f + __expf(-val));
        float c2 = (bf2f(c2v[j]) - mcv) * icv * g4[j] + b4[j];
        float iv = bf2f(iv4[j]);
        float ht =
            fmaxf(k4[j] * (iv + c2) + fmaxf(o4[j], 0.f) * (iv * c2), 0.f);
        out_f32[bofs + (size_t)(m0 + j) * HW_ + n] =
            (1.f - g2) * bf2f(hx4[j]) + g2 * ht;
      }
    }
  }
}

// ---- conv7 PLAIN: round-9 staging (DMA weights + register-path input);
// ---- store conv result cl + own LN stats (full restrict) -------------------
__global__ __launch_bounds__(256, 2) void conv7_plain_k(
    const unsigned short* __restrict__ in_cl,
    const unsigned short* __restrict__ Wp, unsigned short* __restrict__ out,
    float* __restrict__ mu_o, float* __restrict__ inv_o) {
  __shared__ short w_s[7 * 4 * 128 * 8];   // 57344 B
  __shared__ short in_s[2 * 4 * 136 * 8];  // 17408 B
  int b = blockIdx.x & 7;
  int y0 = ((blockIdx.x >> 3) & 63) * 2;
  int tid = threadIdx.x;
  int lane = tid & 63;
  int wid = tid >> 6;
  int wm = wid >> 1;
  int row = wid & 1;
  int l15 = lane & 15, kg = lane >> 4;
  f32x4 acc[4][8] = {};
  for (int ky = 0; ky < 7; ++ky) {
    int ybase = y0 + ky - 3;
    for (int c4 = 0; c4 < 4; ++c4) {
      __syncthreads();
      const unsigned short* wsrc =
          Wp + (size_t)(ky * 7) * 16384 + c4 * 4096 + tid * 8;
#pragma unroll
      for (int kx = 0; kx < 7; ++kx) {
#pragma unroll
        for (int h = 0; h < 2; ++h) {
          async_copy16(w_s + kx * 4096 + (h * 256 + tid) * 8,
                       wsrc + kx * 16384 + h * 2048);
        }
      }
      for (int u = tid; u < 1088; u += 256) {
        int r = u / 544;
        int rem = u - r * 544;
        int g = rem / 136;
        int xi = rem - g * 136;
        int x = xi - 3;
        int y = ybase + r;
        u16x8 v = {};
        if (x >= 0 && x < 128 && y >= 0 && y < 128)
          v = *(const u16x8*)(in_cl + ((size_t)((b * 128 + y) * 128 + x) * 128 +
                                       c4 * 32 + g * 8));
        *(u16x8*)(in_s + u * 8) = v;
      }
      __syncthreads();
      for (int kx = 0; kx < 7; ++kx) {
        bf16x8 bfr[8], afr[4];
#pragma unroll
        for (int nf = 0; nf < 8; ++nf) {
          int xi = nf * 16 + l15 + kx;
          bfr[nf] = *(const bf16x8*)(in_s + ((row * 4 + kg) * 136 + xi) * 8);
        }
#pragma unroll
        for (int mf = 0; mf < 4; ++mf) {
          int oc = wm * 64 + mf * 16 + l15;
          afr[mf] = *(const bf16x8*)(w_s + ((kx * 4 + kg) * 128 + oc) * 8);
        }
#pragma unroll
        for (int mf = 0; mf < 4; ++mf)
#pragma unroll
          for (int nf = 0; nf < 8; ++nf)
            acc[mf][nf] = __builtin_amdgcn_mfma_f32_16x16x32_bf16(
                afr[mf], bfr[nf], acc[mf][nf], 0, 0, 0);
      }
    }
  }
  __syncthreads();
  float* red = (float*)in_s;
  int y = y0 + row;
#pragma unroll
  for (int nf = 0; nf < 8; ++nf) {
    int x = nf * 16 + l15;
    size_t paddr = (size_t)(b * HW_ + y * 128 + x) * 128;
    float s = 0.f, qq = 0.f;
#pragma unroll
    for (int mf = 0; mf < 4; ++mf) {
      int oc0 = wm * 64 + mf * 16 + kg * 4;
      u16x4 st;
#pragma unroll
      for (int j = 0; j < 4; ++j) {
        unsigned short bv = f2bf(acc[mf][nf][j]);
        float vr = bf2f(bv);
        s += vr;
        qq = fmaf(vr, vr, qq);
        st[j] = bv;
      }
      *(u16x4*)(out + paddr + oc0) = st;
    }
    s += __shfl_xor(s, 16);
    qq += __shfl_xor(qq, 16);
    s += __shfl_xor(s, 32);
    qq += __shfl_xor(qq, 32);
    if (kg == 0) {
      red[(wm * 2 + row) * 128 + x] = s;
      red[512 + (wm * 2 + row) * 128 + x] = qq;
    }
  }
  __syncthreads();
  {
    int r2 = tid >> 7, x2 = tid & 127;
    float s = red[r2 * 128 + x2] + red[(2 + r2) * 128 + x2];
    float qq = red[512 + r2 * 128 + x2] + red[512 + (2 + r2) * 128 + x2];
    float m = s * (1.f / 128.f);
    float var = qq * (1.f / 128.f) - m * m;
    int q = b * HW_ + (y0 + r2) * 128 + x2;
    mu_o[q] = m;
    inv_o[q] = rsqrtf(var + 1e-5f);
  }
}

// ---- conv7 FUSED: round-9 staging; LN(c1)+inhibit in-register, writes ------
// ---- INHIBITED cl (out aliases ff_cl); emits g2 LN stats via ps12/pq12 -----
__global__ __launch_bounds__(256, 2) void conv7_inh_k(
    const unsigned short* __restrict__ in_cl,
    const unsigned short* __restrict__ Wp, unsigned short* out,
    float* __restrict__ mu_o, float* __restrict__ inv_o,
    const unsigned short* ff_cl, const unsigned short* __restrict__ hinh_cl,
    const float* __restrict__ ps12, const float* __restrict__ pq12,
    const float* __restrict__ sig_alpha, const float* __restrict__ mu_p,
    const float* __restrict__ gamma, const float* __restrict__ beta) {
  __shared__ short w_s[7 * 4 * 128 * 8];   // 57344 B
  __shared__ short in_s[2 * 4 * 136 * 8];  // 17408 B
  int b = blockIdx.x & 7;
  int y0 = ((blockIdx.x >> 3) & 63) * 2;
  int tid = threadIdx.x;
  int lane = tid & 63;
  int wid = tid >> 6;
  int wm = wid >> 1;
  int row = wid & 1;
  int l15 = lane & 15, kg = lane >> 4;
  f32x4 acc[4][8] = {};
  for (int ky = 0; ky < 7; ++ky) {
    int ybase = y0 + ky - 3;
    for (int c4 = 0; c4 < 4; ++c4) {
      __syncthreads();
      const unsigned short* wsrc =
          Wp + (size_t)(ky * 7) * 16384 + c4 * 4096 + tid * 8;
#pragma unroll
      for (int kx = 0; kx < 7; ++kx) {
#pragma unroll
        for (int h = 0; h < 2; ++h) {
          async_copy16(w_s + kx * 4096 + (h * 256 + tid) * 8,
                       wsrc + kx * 16384 + h * 2048);
        }
      }
      for (int u = tid; u < 1088; u += 256) {
        int r = u / 544;
        int rem = u - r * 544;
        int g = rem / 136;
        int xi = rem - g * 136;
        int x = xi - 3;
        int y = ybase + r;
        u16x8 v = {};
        if (x >= 0 && x < 128 && y >= 0 && y < 128)
          v = *(const u16x8*)(in_cl + ((size_t)((b * 128 + y) * 128 + x) * 128 +
                                       c4 * 32 + g * 8));
        *(u16x8*)(in_s + u * 8) = v;
      }
      __syncthreads();
      for (int kx = 0; kx < 7; ++kx) {
        bf16x8 bfr[8], afr[4];
#pragma unroll
        for (int nf = 0; nf < 8; ++nf) {
          int xi = nf * 16 + l15 + kx;
          bfr[nf] = *(const bf16x8*)(in_s + ((row * 4 + kg) * 136 + xi) * 8);
        }
#pragma unroll
        for (int mf = 0; mf < 4; ++mf) {
          int oc = wm * 64 + mf * 16 + l15;
          afr[mf] = *(const bf16x8*)(w_s + ((kx * 4 + kg) * 128 + oc) * 8);
        }
#pragma unroll
        for (int mf = 0; mf < 4; ++mf)
#pragma unroll
          for (int nf = 0; nf < 8; ++nf)
            acc[mf][nf] = __builtin_amdgcn_mfma_f32_16x16x32_bf16(
                afr[mf], bfr[nf], acc[mf][nf], 0, 0, 0);
      }
    }
  }
  __syncthreads();
  float* red = (float*)in_s;  // [0..511]=s, [512..1023]=q, [1024..1535]=mu/inv
  int y = y0 + row;
  // phase A: LN stats of bf16-rounded conv result
#pragma unroll
  for (int nf = 0; nf < 8; ++nf) {
    int x = nf * 16 + l15;
    float s = 0.f, qq = 0.f;
#pragma unroll
    for (int mf = 0; mf < 4; ++mf) {
#pragma unroll
      for (int j = 0; j < 4; ++j) {
        float vr = bf2f(f2bf(acc[mf][nf][j]));
        s += vr;
        qq = fmaf(vr, vr, qq);
      }
    }
    s += __shfl_xor(s, 16);
    qq += __shfl_xor(qq, 16);
    s += __shfl_xor(s, 32);
    qq += __shfl_xor(qq, 32);
    if (kg == 0) {
      red[(wm * 2 + row) * 128 + x] = s;
      red[512 + (wm * 2 + row) * 128 + x] = qq;
    }
  }
  __syncthreads();
  // phase B: finalize c1 LN stats into LDS
  {
    int r2 = tid >> 7, x2 = tid & 127;
    float s = red[r2 * 128 + x2] + red[(2 + r2) * 128 + x2];
    float qq = red[512 + r2 * 128 + x2] + red[512 + (2 + r2) * 128 + x2];
    float m = s * (1.f / 128.f);
    float var = qq * (1.f / 128.f) - m * m;
    red[1024 + r2 * 128 + x2] = m;
    red[1280 + r2 * 128 + x2] = rsqrtf(var + 1e-5f);
  }
  __syncthreads();
  // phase C: LN + inhibit in-register, write inhibited, sum for g2 LN
  f32x4 ga4[4], be4[4], sa4[4], mp4[4];
#pragma unroll
  for (int mf = 0; mf < 4; ++mf) {
    int oc0 = wm * 64 + mf * 16 + kg * 4;
    ga4[mf] = *(const f32x4*)(gamma + oc0);
    be4[mf] = *(const f32x4*)(beta + oc0);
    sa4[mf] = *(const f32x4*)(sig_alpha + oc0);
    mp4[mf] = *(const f32x4*)(mu_p + oc0);
  }
#pragma unroll
  for (int nf = 0; nf < 8; ++nf) {
    int x = nf * 16 + l15;
    float muv = red[1024 + row * 128 + x];
    float invv = red[1280 + row * 128 + x];
    size_t paddr = (size_t)(b * HW_ + y * 128 + x) * 128;
    float s2 = 0.f, q2 = 0.f;
#pragma unroll
    for (int mf = 0; mf < 4; ++mf) {
      int oc0 = wm * 64 + mf * 16 + kg * 4;
      u16x4 ffv = *(const u16x4*)(ff_cl + paddr + oc0);
      u16x4 hiv = *(const u16x4*)(hinh_cl + paddr + oc0);
      u16x4 st;
#pragma unroll
      for (int j = 0; j < 4; ++j) {
        float c1 =
            (bf2f(f2bf(acc[mf][nf][j])) - muv) * invv * ga4[mf][j] + be4[mf][j];
        float r = fmaxf((sa4[mf][j] * bf2f(hiv[j]) + mp4[mf][j]) * c1, 0.f);
        float v = fmaxf(bf2f(ffv[j]) - r, 0.f);
        unsigned short bv = f2bf(v);
        float vr = bf2f(bv);
        s2 += vr;
        q2 = fmaf(vr, vr, q2);
        st[j] = bv;
      }
      *(u16x4*)(out + paddr + oc0) = st;
    }
    s2 += __shfl_xor(s2, 16);
    q2 += __shfl_xor(q2, 16);
    s2 += __shfl_xor(s2, 32);
    q2 += __shfl_xor(q2, 32);
    if (kg == 0) {
      red[(wm * 2 + row) * 128 + x] = s2;
      red[512 + (wm * 2 + row) * 128 + x] = q2;
    }
  }
  __syncthreads();
  // phase D: g2 LN stats = inhibited sums + (h_exc,h_inh) partials
  {
    int r2 = tid >> 7, x2 = tid & 127;
    float s = red[r2 * 128 + x2] + red[(2 + r2) * 128 + x2];
    float qq = red[512 + r2 * 128 + x2] + red[512 + (2 + r2) * 128 + x2];
    int pg = b * HW_ + (y0 + r2) * 128 + x2;
    s += ps12[pg];
    qq += pq12[pg];
    float m = s * (1.f / 384.f);
    float var = qq * (1.f / 384.f) - m * m;
    mu_o[pg] = m;
    inv_o[pg] = rsqrtf(var + 1e-5f);
  }
}

extern "C" void kernel_launch(void* const* d_in, const int* in_sizes, int n_in,
                              void* d_out, int out_size, void* d_ws,
                              size_t ws_size, hipStream_t stream) {
  const float* ff     = (const float*)d_in[0];
  const float* h_exc  = (const float*)d_in[1];
  const float* h_inh  = (const float*)d_in[2];
  const float* W_gain = (const float*)d_in[3];
  const float* b_gain = (const float*)d_in[4];
  const float* W_mix  = (const float*)d_in[5];
  const float* b_mix  = (const float*)d_in[6];
  const float* W_inh  = (const float*)d_in[7];
  const float* W_exc  = (const float*)d_in[8];
  const float* alpha  = (const float*)d_in[9];
  const float* mu_p   = (const float*)d_in[10];
  const float* kappa  = (const float*)d_in[11];
  const float* omega  = (const float*)d_in[12];
  const float* c1_g   = (const float*)d_in[13];
  const float* c1_b   = (const float*)d_in[14];
  const float* c2_g   = (const float*)d_in[15];
  const float* c2_b   = (const float*)d_in[16];

  float* w = (float*)d_ws;
  unsigned short* Wp_inh = (unsigned short*)w;  w += 401408;
  unsigned short* Wp_exc = (unsigned short*)w;  w += 401408;
  unsigned short* Ag     = (unsigned short*)w;  w += 24576;
  unsigned short* Am     = (unsigned short*)w;  w += 24576;
  float* rs     = w;  w += 256;
  float* sa     = w;  w += 128;    // sigmoid(alpha)
  float* mu2    = w;  w += NPIX_;
  float* inv2   = w;  w += NPIX_;
  float* mu_c2  = w;  w += NPIX_;
  float* inv_c2 = w;  w += NPIX_;
  float* ps12   = w;  w += NPIX_;
  float* pq12   = w;  w += NPIX_;
  unsigned short* exc_cl   = (unsigned short*)w;  w += 8388608;
  unsigned short* hinh_cl  = (unsigned short*)w;  w += 8388608;
  unsigned short* ffinh_cl = (unsigned short*)w;  w += 8388608;  // ff -> inhibited
  unsigned short* conv_cl  = (unsigned short*)w;  w += 8388608;  // c2raw

  unsigned short* gated_cl = (unsigned short*)d_out;  // dead before final write

  prep_w_bf16_k<<<3136, 256, 0, stream>>>(W_inh, W_exc, Wp_inh, Wp_exc);
  prep_apack_k<<<192, 256, 0, stream>>>(W_gain, W_mix, Ag, Am);
  rowsum_k<<<1, 256, 0, stream>>>(W_gain, W_mix, alpha, rs, sa);

  // FUSED: g1 LN stats + cl copies + (h_exc,h_inh) partials + g1 gate GEMM
  // -> gated_cl (d_out)
  stats3_gate_k<<<2048, 256, 0, stream>>>(h_exc, h_inh, ff, Ag, rs, b_gain,
                                          ps12, pq12, exc_cl, hinh_cl,
                                          ffinh_cl, gated_cl);
  // c1 = sym_conv(gated) with FUSED LN+inhibit+g2-stats epilogue.
  conv7_inh_k<<<512, 256, 0, stream>>>(gated_cl, Wp_inh, ffinh_cl, mu2, inv2,
                                       ffinh_cl, hinh_cl, ps12, pq12, sa, mu_p,
                                       c1_g, c1_b);
  // c2 = sym_conv(inhibited) + plain LN-stats epilogue
  conv7_plain_k<<<512, 256, 0, stream>>>(ffinh_cl, Wp_exc, conv_cl, mu_c2,
                                         inv_c2);
  // g2 gemm + fused final mix -> d_out f32 NCHW
  {
    dim3 g(128, 8);
    gemm_final_k<<<g, 256, 0, stream>>>(
        Am, rs + 128, b_mix, ffinh_cl, exc_cl, hinh_cl, mu2, inv2, conv_cl,
        mu_c2, inv_c2, ffinh_cl, exc_cl, c2_g, c2_b, kappa, omega,
        (float*)d_out);
  }
}

// Round 16
// 558.379 us; speedup vs baseline: 1.2378x; 1.0064x over previous
//
#include <hip/hip_runtime.h>
#include <cstddef>
#include <cstdint>

namespace {
constexpr int B_ = 8, C_ = 128, H_ = 128, W_ = 128;
constexpr int HW_ = H_ * W_;               // 16384
constexpr size_t CHW_ = (size_t)C_ * HW_;  // 2097152
constexpr int NPIX_ = B_ * HW_;            // 131072
}

typedef __attribute__((ext_vector_type(8))) short bf16x8;
typedef __attribute__((ext_vector_type(4))) float f32x4;
typedef __attribute__((ext_vector_type(2))) float f32x2;
typedef __attribute__((ext_vector_type(8))) unsigned short u16x8;
typedef __attribute__((ext_vector_type(4))) unsigned short u16x4;

__device__ inline unsigned short f2bf(float f) {
  unsigned int u = __float_as_uint(f);
  unsigned int r = u + 0x7FFFu + ((u >> 16) & 1u);
  return (unsigned short)(r >> 16);
}
__device__ inline float bf2f(unsigned short u) {
  return __uint_as_float((unsigned int)u << 16);
}

// async 16B global->LDS DMA (per-lane addr = wave base + lane*16)
__device__ inline void async_copy16(void* lds_dst, const void* gsrc) {
  __builtin_amdgcn_global_load_lds(
      (const __attribute__((address_space(1))) unsigned int*)gsrc,
      (__attribute__((address_space(3))) unsigned int*)lds_dst, 16, 0, 0);
}

// ---- conv weight prep: symmetrize, bf16, layout [tap49][grp16][oc128][ic8]
__global__ __launch_bounds__(256) void prep_w_bf16_k(
    const float* __restrict__ Wa, const float* __restrict__ Wb,
    unsigned short* __restrict__ Ta, unsigned short* __restrict__ Tb) {
  int idx = blockIdx.x * 256 + threadIdx.x;  // 802816
  int j = idx & 7;
  int o = (idx >> 3) & 127;
  int g = (idx >> 10) & 15;
  int t = idx >> 14;
  int i = g * 8 + j;
  int ky = t / 7, kx = t - ky * 7;
  size_t oi = ((size_t)(o * 128 + i) * 7 + ky) * 7 + kx;
  size_t io = ((size_t)(i * 128 + o) * 7 + ky) * 7 + kx;
  Ta[idx] = f2bf(0.5f * (Wa[oi] + Wa[io]));
  Tb[idx] = f2bf(0.5f * (Wb[oi] + Wb[io]));
}

// ---- 1x1 weight prep: bf16 fragment layout [s12][f8][lane64][j8] -----------
__global__ __launch_bounds__(256) void prep_apack_k(
    const float* __restrict__ Wg, const float* __restrict__ Wm,
    unsigned short* __restrict__ Ag, unsigned short* __restrict__ Am) {
  int idx = blockIdx.x * 256 + threadIdx.x;  // 49152
  int j = idx & 7;
  int l = (idx >> 3) & 63;
  int f = (idx >> 9) & 7;
  int s = idx >> 12;
  int m = f * 16 + (l & 15);
  int k = s * 32 + (l >> 4) * 8 + j;
  Ag[idx] = f2bf(Wg[m * 384 + k]);
  Am[idx] = f2bf(Wm[m * 384 + k]);
}

// ---- row sums of the 1x1 weights (LN folding) + sigmoid(alpha) table -------
__global__ void rowsum_k(const float* __restrict__ Wg,
                         const float* __restrict__ Wm,
                         const float* __restrict__ alpha,
                         float* __restrict__ rs, float* __restrict__ sa) {
  int t = threadIdx.x;
  const float* src = (t < 128) ? Wg : Wm;
  int row = t & 127;
  float s = 0.f;
  for (int i = 0; i < 384; ++i) s += bf2f(f2bf(src[row * 384 + i]));
  rs[t] = s;
  if (t < 128) sa[t] = 1.f / (1.f + __expf(-alpha[t]));
}

// ---- FUSED: LN stats over [h_exc,h_inh,ff] + cl bf16 copies + ps12/pq12
// ---- partials + the FULL g1 gate GEMM (per-tensor K-slices from the live
// ---- LDS tile) + gated = h_exc*g1 epilogue. Replaces stats3 + gemm0.
// Block: 64 px, 256 thr = 4 waves; wave = 16 px x 128 oc (8 mf fragments).
__global__ __launch_bounds__(256) void stats3_gate_k(
    const float* __restrict__ t0, const float* __restrict__ t1,
    const float* __restrict__ t2, const unsigned short* __restrict__ Apack,
    const float* __restrict__ rowsum, const float* __restrict__ bias,
    float* __restrict__ ps12, float* __restrict__ pq12,
    unsigned short* __restrict__ o0, unsigned short* __restrict__ o1,
    unsigned short* __restrict__ o2, unsigned short* __restrict__ gated_cl) {
  __shared__ unsigned short tile[64 * 136];  // current tensor, 64px x 128c
  __shared__ unsigned short exc2[64 * 128];  // h_exc copy for gating mult
  __shared__ float s8[8][64];
  __shared__ float q8[8][64];
  __shared__ float bc_mu[64];
  __shared__ float bc_inv[64];
  int blk = blockIdx.x;  // 2048 = 8 b x 256
  int b = blk >> 8;
  int p0 = (blk & 255) * 64;
  int t = threadIdx.x;
  int px2 = (t & 31) * 2, cq = t >> 5;
  int lane = t & 63, wv = t >> 6;
  int l15 = lane & 15, kg = lane >> 4;
  size_t base = (size_t)b * CHW_ + p0 + px2;
  int pixg = b * HW_ + p0;
  f32x4 acc[8] = {};
  float s0a = 0.f, s0b = 0.f, q0a = 0.f, q0b = 0.f;

  // ======== pass 0: h_exc ========
  for (int ci = 0; ci < 16; ++ci) {
    int c = cq * 16 + ci;
    f32x2 v = *(const f32x2*)(t0 + base + (size_t)c * HW_);
    s0a += v[0]; q0a = fmaf(v[0], v[0], q0a);
    s0b += v[1]; q0b = fmaf(v[1], v[1], q0b);
    unsigned short b0 = f2bf(v[0]), b1 = f2bf(v[1]);
    tile[px2 * 136 + c] = b0;
    tile[(px2 + 1) * 136 + c] = b1;
    exc2[px2 * 128 + c] = b0;
    exc2[(px2 + 1) * 128 + c] = b1;
  }
  __syncthreads();
#pragma unroll
  for (int pass = 0; pass < 4; ++pass) {
    int u = pass * 256 + t;
    int ppx = u >> 4, cg = u & 15;
    *(u16x8*)(o0 + (size_t)(pixg + ppx) * 128 + cg * 8) =
        *(const u16x8*)(tile + ppx * 136 + cg * 8);
  }
  // gate MFMA: K-slices 0..3 (tensor 0) from live tile
#pragma unroll
  for (int sl = 0; sl < 4; ++sl) {
    bf16x8 bfr =
        *(const bf16x8*)(tile + (wv * 16 + l15) * 136 + sl * 32 + kg * 8);
    const bf16x8* ap =
        (const bf16x8*)(Apack + ((size_t)(sl * 8) * 64 + lane) * 8);
#pragma unroll
    for (int f = 0; f < 8; ++f)
      acc[f] = __builtin_amdgcn_mfma_f32_16x16x32_bf16(ap[f * 64], bfr, acc[f],
                                                       0, 0, 0);
  }
  __syncthreads();

  // ======== pass 1: h_inh ========
  for (int ci = 0; ci < 16; ++ci) {
    int c = cq * 16 + ci;
    f32x2 v = *(const f32x2*)(t1 + base + (size_t)c * HW_);
    s0a += v[0]; q0a = fmaf(v[0], v[0], q0a);
    s0b += v[1]; q0b = fmaf(v[1], v[1], q0b);
    tile[px2 * 136 + c] = f2bf(v[0]);
    tile[(px2 + 1) * 136 + c] = f2bf(v[1]);
  }
  s8[cq][px2] = s0a;
  s8[cq][px2 + 1] = s0b;
  q8[cq][px2] = q0a;
  q8[cq][px2 + 1] = q0b;
  __syncthreads();
#pragma unroll
  for (int pass = 0; pass < 4; ++pass) {
    int u = pass * 256 + t;
    int ppx = u >> 4, cg = u & 15;
    *(u16x8*)(o1 + (size_t)(pixg + ppx) * 128 + cg * 8) =
        *(const u16x8*)(tile + ppx * 136 + cg * 8);
  }
#pragma unroll
  for (int sl = 0; sl < 4; ++sl) {
    bf16x8 bfr =
        *(const bf16x8*)(tile + (wv * 16 + l15) * 136 + sl * 32 + kg * 8);
    const bf16x8* ap =
        (const bf16x8*)(Apack + ((size_t)((4 + sl) * 8) * 64 + lane) * 8);
#pragma unroll
    for (int f = 0; f < 8; ++f)
      acc[f] = __builtin_amdgcn_mfma_f32_16x16x32_bf16(ap[f * 64], bfr, acc[f],
                                                       0, 0, 0);
  }
  if (t < 64) {
    float ss = 0.f, qs = 0.f;
#pragma unroll
    for (int k = 0; k < 8; ++k) { ss += s8[k][t]; qs += q8[k][t]; }
    ps12[pixg + t] = ss;
    pq12[pixg + t] = qs;
  }
  __syncthreads();

  // ======== pass 2: ff ========
  for (int ci = 0; ci < 16; ++ci) {
    int c = cq * 16 + ci;
    f32x2 v = *(const f32x2*)(t2 + base + (size_t)c * HW_);
    s0a += v[0]; q0a = fmaf(v[0], v[0], q0a);
    s0b += v[1]; q0b = fmaf(v[1], v[1], q0b);
    tile[px2 * 136 + c] = f2bf(v[0]);
    tile[(px2 + 1) * 136 + c] = f2bf(v[1]);
  }
  s8[cq][px2] = s0a;
  s8[cq][px2 + 1] = s0b;
  q8[cq][px2] = q0a;
  q8[cq][px2 + 1] = q0b;
  __syncthreads();
#pragma unroll
  for (int pass = 0; pass < 4; ++pass) {
    int u = pass * 256 + t;
    int ppx = u >> 4, cg = u & 15;
    *(u16x8*)(o2 + (size_t)(pixg + ppx) * 128 + cg * 8) =
        *(const u16x8*)(tile + ppx * 136 + cg * 8);
  }
#pragma unroll
  for (int sl = 0; sl < 4; ++sl) {
    bf16x8 bfr =
        *(const bf16x8*)(tile + (wv * 16 + l15) * 136 + sl * 32 + kg * 8);
    const bf16x8* ap =
        (const bf16x8*)(Apack + ((size_t)((8 + sl) * 8) * 64 + lane) * 8);
#pragma unroll
    for (int f = 0; f < 8; ++f)
      acc[f] = __builtin_amdgcn_mfma_f32_16x16x32_bf16(ap[f * 64], bfr, acc[f],
                                                       0, 0, 0);
  }
  if (t < 64) {
    float ss = 0.f, qs = 0.f;
#pragma unroll
    for (int k = 0; k < 8; ++k) { ss += s8[k][t]; qs += q8[k][t]; }
    float m = ss * (1.f / 384.f);
    float var = qs * (1.f / 384.f) - m * m;
    bc_mu[t] = m;
    bc_inv[t] = rsqrtf(var + 1e-5f);
  }
  __syncthreads();

  // ======== epilogue: g1 = sigmoid(LNfold); gated = h_exc * g1 ========
  {
    int pxl = wv * 16 + l15;
    int pix = pixg + pxl;
    float muv = bc_mu[pxl], invv = bc_inv[pxl];
#pragma unroll
    for (int f = 0; f < 8; ++f) {
      int m0 = f * 16 + kg * 4;
      f32x4 rs4 = *(const f32x4*)(rowsum + m0);
      f32x4 bi4 = *(const f32x4*)(bias + m0);
      u16x4 mv = *(const u16x4*)(exc2 + pxl * 128 + m0);
      u16x4 st;
#pragma unroll
      for (int j = 0; j < 4; ++j) {
        float val = invv * (acc[f][j] - muv * rs4[j]) + bi4[j];
        float g = 1.f / (1.f + __expf(-val));
        st[j] = f2bf(bf2f(mv[j]) * g);
      }
      *(u16x4*)(gated_cl + (size_t)pix * 128 + m0) = st;
    }
  }
}

// ---- MFMA g2 gate GEMM + fused final mix (FINAL epilogue only) -------------
__global__ __launch_bounds__(256) void gemm_final_k(
    const unsigned short* __restrict__ Apack, const float* __restrict__ rowsum,
    const float* __restrict__ bias, const unsigned short* __restrict__ B0,
    const unsigned short* __restrict__ B1, const unsigned short* __restrict__ B2,
    const float* __restrict__ mu, const float* __restrict__ inv,
    const unsigned short* __restrict__ c2_cl, const float* __restrict__ muc,
    const float* __restrict__ invc, const unsigned short* __restrict__ inh_cl,
    const unsigned short* __restrict__ hexc_cl, const float* __restrict__ c2g,
    const float* __restrict__ c2b, const float* __restrict__ kap,
    const float* __restrict__ omg, float* __restrict__ out_f32) {
  int b = blockIdx.y;
  int tid = threadIdx.x;
  int lane = tid & 63, wid = tid >> 6;
  int l15 = lane & 15, kg = lane >> 4;
  int n0 = blockIdx.x * 128 + wid * 32;
  int pix0 = b * HW_ + n0;
  size_t bofs = (size_t)b * CHW_;
  f32x4 acc[8][2] = {};
#pragma unroll
  for (int s = 0; s < 12; ++s) {
    const unsigned short* src = (s < 4) ? B0 : ((s < 8) ? B1 : B2);
    int ch0 = (s & 3) * 32 + kg * 8;
    bf16x8 bfr[2];
#pragma unroll
    for (int nf = 0; nf < 2; ++nf)
      bfr[nf] = *(const bf16x8*)(src + (size_t)(pix0 + nf * 16 + l15) * 128 + ch0);
    const bf16x8* ap = (const bf16x8*)(Apack + ((size_t)(s * 8) * 64 + lane) * 8);
#pragma unroll
    for (int f = 0; f < 8; ++f) {
      bf16x8 afr = ap[f * 64];
#pragma unroll
      for (int nf = 0; nf < 2; ++nf)
        acc[f][nf] = __builtin_amdgcn_mfma_f32_16x16x32_bf16(afr, bfr[nf],
                                                             acc[f][nf], 0, 0, 0);
    }
  }
#pragma unroll
  for (int nf = 0; nf < 2; ++nf) {
    int n = n0 + nf * 16 + l15;
    int qpix = b * HW_ + n;
    float muv = mu[qpix], invv = inv[qpix];
    float mcv = muc[qpix], icv = invc[qpix];
#pragma unroll
    for (int mf = 0; mf < 8; ++mf) {
      int m0 = mf * 16 + kg * 4;
      f32x4 rs4 = *(const f32x4*)(rowsum + m0);
      f32x4 bi4 = *(const f32x4*)(bias + m0);
      f32x4 g4 = *(const f32x4*)(c2g + m0);
      f32x4 b4 = *(const f32x4*)(c2b + m0);
      f32x4 k4 = *(const f32x4*)(kap + m0);
      f32x4 o4 = *(const f32x4*)(omg + m0);
      u16x4 c2v = *(const u16x4*)(c2_cl + (size_t)qpix * 128 + m0);
      u16x4 iv4 = *(const u16x4*)(inh_cl + (size_t)qpix * 128 + m0);
      u16x4 hx4 = *(const u16x4*)(hexc_cl + (size_t)qpix * 128 + m0);
#pragma unroll
      for (int j = 0; j < 4; ++j) {
        float val = invv * (acc[mf][nf][j] - muv * rs4[j]) + bi4[j];
        float g2 = 1.f / (1.f + __expf(-val));
        float c2 = (bf2f(c2v[j]) - mcv) * icv * g4[j] + b4[j];
        float iv = bf2f(iv4[j]);
        float ht =
            fmaxf(k4[j] * (iv + c2) + fmaxf(o4[j], 0.f) * (iv * c2), 0.f);
        out_f32[bofs + (size_t)(m0 + j) * HW_ + n] =
            (1.f - g2) * bf2f(hx4[j]) + g2 * ht;
      }
    }
  }
}

// ---- conv7 PLAIN: round-9 staging (DMA weights + register-path input);
// ---- store conv result cl + own LN stats (full restrict); T5 setprio -------
__global__ __launch_bounds__(256, 2) void conv7_plain_k(
    const unsigned short* __restrict__ in_cl,
    const unsigned short* __restrict__ Wp, unsigned short* __restrict__ out,
    float* __restrict__ mu_o, float* __restrict__ inv_o) {
  __shared__ short w_s[7 * 4 * 128 * 8];   // 57344 B
  __shared__ short in_s[2 * 4 * 136 * 8];  // 17408 B
  int b = blockIdx.x & 7;
  int y0 = ((blockIdx.x >> 3) & 63) * 2;
  int tid = threadIdx.x;
  int lane = tid & 63;
  int wid = tid >> 6;
  int wm = wid >> 1;
  int row = wid & 1;
  int l15 = lane & 15, kg = lane >> 4;
  f32x4 acc[4][8] = {};
  for (int ky = 0; ky < 7; ++ky) {
    int ybase = y0 + ky - 3;
    for (int c4 = 0; c4 < 4; ++c4) {
      __syncthreads();
      const unsigned short* wsrc =
          Wp + (size_t)(ky * 7) * 16384 + c4 * 4096 + tid * 8;
#pragma unroll
      for (int kx = 0; kx < 7; ++kx) {
#pragma unroll
        for (int h = 0; h < 2; ++h) {
          async_copy16(w_s + kx * 4096 + (h * 256 + tid) * 8,
                       wsrc + kx * 16384 + h * 2048);
        }
      }
      for (int u = tid; u < 1088; u += 256) {
        int r = u / 544;
        int rem = u - r * 544;
        int g = rem / 136;
        int xi = rem - g * 136;
        int x = xi - 3;
        int y = ybase + r;
        u16x8 v = {};
        if (x >= 0 && x < 128 && y >= 0 && y < 128)
          v = *(const u16x8*)(in_cl + ((size_t)((b * 128 + y) * 128 + x) * 128 +
                                       c4 * 32 + g * 8));
        *(u16x8*)(in_s + u * 8) = v;
      }
      __syncthreads();
      __builtin_amdgcn_s_setprio(1);  // T5: favor compute waves vs other
                                      // block's staging waves on this CU
      for (int kx = 0; kx < 7; ++kx) {
        bf16x8 bfr[8], afr[4];
#pragma unroll
        for (int nf = 0; nf < 8; ++nf) {
          int xi = nf * 16 + l15 + kx;
          bfr[nf] = *(const bf16x8*)(in_s + ((row * 4 + kg) * 136 + xi) * 8);
        }
#pragma unroll
        for (int mf = 0; mf < 4; ++mf) {
          int oc = wm * 64 + mf * 16 + l15;
          afr[mf] = *(const bf16x8*)(w_s + ((kx * 4 + kg) * 128 + oc) * 8);
        }
#pragma unroll
        for (int mf = 0; mf < 4; ++mf)
#pragma unroll
          for (int nf = 0; nf < 8; ++nf)
            acc[mf][nf] = __builtin_amdgcn_mfma_f32_16x16x32_bf16(
                afr[mf], bfr[nf], acc[mf][nf], 0, 0, 0);
      }
      __builtin_amdgcn_s_setprio(0);
    }
  }
  __syncthreads();
  float* red = (float*)in_s;
  int y = y0 + row;
#pragma unroll
  for (int nf = 0; nf < 8; ++nf) {
    int x = nf * 16 + l15;
    size_t paddr = (size_t)(b * HW_ + y * 128 + x) * 128;
    float s = 0.f, qq = 0.f;
#pragma unroll
    for (int mf = 0; mf < 4; ++mf) {
      int oc0 = wm * 64 + mf * 16 + kg * 4;
      u16x4 st;
#pragma unroll
      for (int j = 0; j < 4; ++j) {
        unsigned short bv = f2bf(acc[mf][nf][j]);
        float vr = bf2f(bv);
        s += vr;
        qq = fmaf(vr, vr, qq);
        st[j] = bv;
      }
      *(u16x4*)(out + paddr + oc0) = st;
    }
    s += __shfl_xor(s, 16);
    qq += __shfl_xor(qq, 16);
    s += __shfl_xor(s, 32);
    qq += __shfl_xor(qq, 32);
    if (kg == 0) {
      red[(wm * 2 + row) * 128 + x] = s;
      red[512 + (wm * 2 + row) * 128 + x] = qq;
    }
  }
  __syncthreads();
  {
    int r2 = tid >> 7, x2 = tid & 127;
    float s = red[r2 * 128 + x2] + red[(2 + r2) * 128 + x2];
    float qq = red[512 + r2 * 128 + x2] + red[512 + (2 + r2) * 128 + x2];
    float m = s * (1.f / 128.f);
    float var = qq * (1.f / 128.f) - m * m;
    int q = b * HW_ + (y0 + r2) * 128 + x2;
    mu_o[q] = m;
    inv_o[q] = rsqrtf(var + 1e-5f);
  }
}

// ---- conv7 FUSED: round-9 staging; LN(c1)+inhibit in-register, writes ------
// ---- INHIBITED cl (out aliases ff_cl); emits g2 LN stats; T5 setprio -------
__global__ __launch_bounds__(256, 2) void conv7_inh_k(
    const unsigned short* __restrict__ in_cl,
    const unsigned short* __restrict__ Wp, unsigned short* out,
    float* __restrict__ mu_o, float* __restrict__ inv_o,
    const unsigned short* ff_cl, const unsigned short* __restrict__ hinh_cl,
    const float* __restrict__ ps12, const float* __restrict__ pq12,
    const float* __restrict__ sig_alpha, const float* __restrict__ mu_p,
    const float* __restrict__ gamma, const float* __restrict__ beta) {
  __shared__ short w_s[7 * 4 * 128 * 8];   // 57344 B
  __shared__ short in_s[2 * 4 * 136 * 8];  // 17408 B
  int b = blockIdx.x & 7;
  int y0 = ((blockIdx.x >> 3) & 63) * 2;
  int tid = threadIdx.x;
  int lane = tid & 63;
  int wid = tid >> 6;
  int wm = wid >> 1;
  int row = wid & 1;
  int l15 = lane & 15, kg = lane >> 4;
  f32x4 acc[4][8] = {};
  for (int ky = 0; ky < 7; ++ky) {
    int ybase = y0 + ky - 3;
    for (int c4 = 0; c4 < 4; ++c4) {
      __syncthreads();
      const unsigned short* wsrc =
          Wp + (size_t)(ky * 7) * 16384 + c4 * 4096 + tid * 8;
#pragma unroll
      for (int kx = 0; kx < 7; ++kx) {
#pragma unroll
        for (int h = 0; h < 2; ++h) {
          async_copy16(w_s + kx * 4096 + (h * 256 + tid) * 8,
                       wsrc + kx * 16384 + h * 2048);
        }
      }
      for (int u = tid; u < 1088; u += 256) {
        int r = u / 544;
        int rem = u - r * 544;
        int g = rem / 136;
        int xi = rem - g * 136;
        int x = xi - 3;
        int y = ybase + r;
        u16x8 v = {};
        if (x >= 0 && x < 128 && y >= 0 && y < 128)
          v = *(const u16x8*)(in_cl + ((size_t)((b * 128 + y) * 128 + x) * 128 +
                                       c4 * 32 + g * 8));
        *(u16x8*)(in_s + u * 8) = v;
      }
      __syncthreads();
      __builtin_amdgcn_s_setprio(1);
      for (int kx = 0; kx < 7; ++kx) {
        bf16x8 bfr[8], afr[4];
#pragma unroll
        for (int nf = 0; nf < 8; ++nf) {
          int xi = nf * 16 + l15 + kx;
          bfr[nf] = *(const bf16x8*)(in_s + ((row * 4 + kg) * 136 + xi) * 8);
        }
#pragma unroll
        for (int mf = 0; mf < 4; ++mf) {
          int oc = wm * 64 + mf * 16 + l15;
          afr[mf] = *(const bf16x8*)(w_s + ((kx * 4 + kg) * 128 + oc) * 8);
        }
#pragma unroll
        for (int mf = 0; mf < 4; ++mf)
#pragma unroll
          for (int nf = 0; nf < 8; ++nf)
            acc[mf][nf] = __builtin_amdgcn_mfma_f32_16x16x32_bf16(
                afr[mf], bfr[nf], acc[mf][nf], 0, 0, 0);
      }
      __builtin_amdgcn_s_setprio(0);
    }
  }
  __syncthreads();
  float* red = (float*)in_s;  // [0..511]=s, [512..1023]=q, [1024..1535]=mu/inv
  int y = y0 + row;
  // phase A: LN stats of bf16-rounded conv result
#pragma unroll
  for (int nf = 0; nf < 8; ++nf) {
    int x = nf * 16 + l15;
    float s = 0.f, qq = 0.f;
#pragma unroll
    for (int mf = 0; mf < 4; ++mf) {
#pragma unroll
      for (int j = 0; j < 4; ++j) {
        float vr = bf2f(f2bf(acc[mf][nf][j]));
        s += vr;
        qq = fmaf(vr, vr, qq);
      }
    }
    s += __shfl_xor(s, 16);
    qq += __shfl_xor(qq, 16);
    s += __shfl_xor(s, 32);
    qq += __shfl_xor(qq, 32);
    if (kg == 0) {
      red[(wm * 2 + row) * 128 + x] = s;
      red[512 + (wm * 2 + row) * 128 + x] = qq;
    }
  }
  __syncthreads();
  // phase B: finalize c1 LN stats into LDS
  {
    int r2 = tid >> 7, x2 = tid & 127;
    float s = red[r2 * 128 + x2] + red[(2 + r2) * 128 + x2];
    float qq = red[512 + r2 * 128 + x2] + red[512 + (2 + r2) * 128 + x2];
    float m = s * (1.f / 128.f);
    float var = qq * (1.f / 128.f) - m * m;
    red[1024 + r2 * 128 + x2] = m;
    red[1280 + r2 * 128 + x2] = rsqrtf(var + 1e-5f);
  }
  __syncthreads();
  // phase C: LN + inhibit in-register, write inhibited, sum for g2 LN
  f32x4 ga4[4], be4[4], sa4[4], mp4[4];
#pragma unroll
  for (int mf = 0; mf < 4; ++mf) {
    int oc0 = wm * 64 + mf * 16 + kg * 4;
    ga4[mf] = *(const f32x4*)(gamma + oc0);
    be4[mf] = *(const f32x4*)(beta + oc0);
    sa4[mf] = *(const f32x4*)(sig_alpha + oc0);
    mp4[mf] = *(const f32x4*)(mu_p + oc0);
  }
#pragma unroll
  for (int nf = 0; nf < 8; ++nf) {
    int x = nf * 16 + l15;
    float muv = red[1024 + row * 128 + x];
    float invv = red[1280 + row * 128 + x];
    size_t paddr = (size_t)(b * HW_ + y * 128 + x) * 128;
    float s2 = 0.f, q2 = 0.f;
#pragma unroll
    for (int mf = 0; mf < 4; ++mf) {
      int oc0 = wm * 64 + mf * 16 + kg * 4;
      u16x4 ffv = *(const u16x4*)(ff_cl + paddr + oc0);
      u16x4 hiv = *(const u16x4*)(hinh_cl + paddr + oc0);
      u16x4 st;
#pragma unroll
      for (int j = 0; j < 4; ++j) {
        float c1 =
            (bf2f(f2bf(acc[mf][nf][j])) - muv) * invv * ga4[mf][j] + be4[mf][j];
        float r = fmaxf((sa4[mf][j] * bf2f(hiv[j]) + mp4[mf][j]) * c1, 0.f);
        float v = fmaxf(bf2f(ffv[j]) - r, 0.f);
        unsigned short bv = f2bf(v);
        float vr = bf2f(bv);
        s2 += vr;
        q2 = fmaf(vr, vr, q2);
        st[j] = bv;
      }
      *(u16x4*)(out + paddr + oc0) = st;
    }
    s2 += __shfl_xor(s2, 16);
    q2 += __shfl_xor(q2, 16);
    s2 += __shfl_xor(s2, 32);
    q2 += __shfl_xor(q2, 32);
    if (kg == 0) {
      red[(wm * 2 + row) * 128 + x] = s2;
      red[512 + (wm * 2 + row) * 128 + x] = q2;
    }
  }
  __syncthreads();
  // phase D: g2 LN stats = inhibited sums + (h_exc,h_inh) partials
  {
    int r2 = tid >> 7, x2 = tid & 127;
    float s = red[r2 * 128 + x2] + red[(2 + r2) * 128 + x2];
    float qq = red[512 + r2 * 128 + x2] + red[512 + (2 + r2) * 128 + x2];
    int pg = b * HW_ + (y0 + r2) * 128 + x2;
    s += ps12[pg];
    qq += pq12[pg];
    float m = s * (1.f / 384.f);
    float var = qq * (1.f / 384.f) - m * m;
    mu_o[pg] = m;
    inv_o[pg] = rsqrtf(var + 1e-5f);
  }
}

extern "C" void kernel_launch(void* const* d_in, const int* in_sizes, int n_in,
                              void* d_out, int out_size, void* d_ws,
                              size_t ws_size, hipStream_t stream) {
  const float* ff     = (const float*)d_in[0];
  const float* h_exc  = (const float*)d_in[1];
  const float* h_inh  = (const float*)d_in[2];
  const float* W_gain = (const float*)d_in[3];
  const float* b_gain = (const float*)d_in[4];
  const float* W_mix  = (const float*)d_in[5];
  const float* b_mix  = (const float*)d_in[6];
  const float* W_inh  = (const float*)d_in[7];
  const float* W_exc  = (const float*)d_in[8];
  const float* alpha  = (const float*)d_in[9];
  const float* mu_p   = (const float*)d_in[10];
  const float* kappa  = (const float*)d_in[11];
  const float* omega  = (const float*)d_in[12];
  const float* c1_g   = (const float*)d_in[13];
  const float* c1_b   = (const float*)d_in[14];
  const float* c2_g   = (const float*)d_in[15];
  const float* c2_b   = (const float*)d_in[16];

  float* w = (float*)d_ws;
  unsigned short* Wp_inh = (unsigned short*)w;  w += 401408;
  unsigned short* Wp_exc = (unsigned short*)w;  w += 401408;
  unsigned short* Ag     = (unsigned short*)w;  w += 24576;
  unsigned short* Am     = (unsigned short*)w;  w += 24576;
  float* rs     = w;  w += 256;
  float* sa     = w;  w += 128;    // sigmoid(alpha)
  float* mu2    = w;  w += NPIX_;
  float* inv2   = w;  w += NPIX_;
  float* mu_c2  = w;  w += NPIX_;
  float* inv_c2 = w;  w += NPIX_;
  float* ps12   = w;  w += NPIX_;
  float* pq12   = w;  w += NPIX_;
  unsigned short* exc_cl   = (unsigned short*)w;  w += 8388608;
  unsigned short* hinh_cl  = (unsigned short*)w;  w += 8388608;
  unsigned short* ffinh_cl = (unsigned short*)w;  w += 8388608;  // ff -> inhibited
  unsigned short* conv_cl  = (unsigned short*)w;  w += 8388608;  // c2raw

  unsigned short* gated_cl = (unsigned short*)d_out;  // dead before final write

  prep_w_bf16_k<<<3136, 256, 0, stream>>>(W_inh, W_exc, Wp_inh, Wp_exc);
  prep_apack_k<<<192, 256, 0, stream>>>(W_gain, W_mix, Ag, Am);
  rowsum_k<<<1, 256, 0, stream>>>(W_gain, W_mix, alpha, rs, sa);

  // FUSED: g1 LN stats + cl copies + (h_exc,h_inh) partials + g1 gate GEMM
  // -> gated_cl (d_out)
  stats3_gate_k<<<2048, 256, 0, stream>>>(h_exc, h_inh, ff, Ag, rs, b_gain,
                                          ps12, pq12, exc_cl, hinh_cl,
                                          ffinh_cl, gated_cl);
  // c1 = sym_conv(gated) with FUSED LN+inhibit+g2-stats epilogue.
  conv7_inh_k<<<512, 256, 0, stream>>>(gated_cl, Wp_inh, ffinh_cl, mu2, inv2,
                                       ffinh_cl, hinh_cl, ps12, pq12, sa, mu_p,
                                       c1_g, c1_b);
  // c2 = sym_conv(inhibited) + plain LN-stats epilogue
  conv7_plain_k<<<512, 256, 0, stream>>>(ffinh_cl, Wp_exc, conv_cl, mu_c2,
                                         inv_c2);
  // g2 gemm + fused final mix -> d_out f32 NCHW
  {
    dim3 g(128, 8);
    gemm_final_k<<<g, 256, 0, stream>>>(
        Am, rs + 128, b_mix, ffinh_cl, exc_cl, hinh_cl, mu2, inv2, conv_cl,
        mu_c2, inv_c2, ffinh_cl, exc_cl, c2_g, c2_b, kappa, omega,
        (float*)d_out);
  }
}